// Round 8
// baseline (362.698 us; speedup 1.0000x reference)
//
#include <hip/hip_runtime.h>
#include <hip/hip_bf16.h>

#define BSZ 16384
#define DD  768
#define KK  4
#define NH1 512
#define NH2 256
#define ND  (KK * DD)   // 3072

typedef __bf16 bf16x8 __attribute__((ext_vector_type(8)));
typedef float  f32x4  __attribute__((ext_vector_type(4)));

static __device__ __forceinline__ float bf2f(ushort u) {
    union { unsigned int i; float f; } v; v.i = (unsigned int)u << 16; return v.f;
}
static __device__ __forceinline__ ushort f2bf(float f) {
    return __bfloat16_as_ushort(__float2bfloat16(f));
}

// ---------------------------------------------------------------------------
// k_t_cvt: src (R x C f32) -> dst (C x R bf16)  [generic transpose+convert]
__global__ __launch_bounds__(256) void k_t_cvt(
    const float* __restrict__ src, ushort* __restrict__ dst, int R, int C)
{
    __shared__ float tile[32][33];
    const int rb0 = blockIdx.y * 32;  // src row
    const int cb0 = blockIdx.x * 32;  // src col
    const int t = threadIdx.x;
    const int r = t >> 5, c = t & 31;
    #pragma unroll
    for (int i = 0; i < 4; ++i)
        tile[r + i * 8][c] = src[(size_t)(rb0 + r + i * 8) * C + cb0 + c];
    __syncthreads();
    #pragma unroll
    for (int i = 0; i < 4; ++i)
        dst[(size_t)(cb0 + r + i * 8) * R + rb0 + c] = f2bf(tile[c][r + i * 8]);
}

// ---------------------------------------------------------------------------
// k1_gemm: h1_raw = emb @ W1 + b1 (bf16). 64x128 tile -> grid 1024 blocks
// (~4 resident/CU; round-7 fix: 128x128 gave only 512 blocks = 2/CU and the
// 12 K-step barrier drains were latency-exposed). BK=64. A fp32->bf16 in-reg.
__global__ __launch_bounds__(256) void k1_gemm(
    const float* __restrict__ emb, const ushort* __restrict__ W1t,
    const float* __restrict__ b1, ushort* __restrict__ h1raw)
{
    __shared__ ushort smem[(64 + 128) * 72];    // Asm | Bsm = 27.6 KB
    ushort* Asm = smem;
    ushort* Bsm = smem + 64 * 72;

    const int t    = threadIdx.x;
    const int lane = t & 63;
    const int wid  = t >> 6;
    const int wm   = wid >> 1;          // 0..1 (32-row half)
    const int wn   = wid & 1;           // 0..1 (64-col half)
    const int l16  = lane & 15;
    const int g8   = (lane >> 4) * 8;
    const int g4   = (lane >> 4) * 4;

    const int rb = blockIdx.y * 64;     // M tile
    const int cb = blockIdx.x * 128;    // N tile (over NH1=512)

    f32x4 acc[2][4] = {};

    for (int ks = 0; ks < 12; ++ks) {
        const int k0 = ks * 64;
        float4 ra0[2], ra1[2];
        int4 rbv[4];
        #pragma unroll
        for (int i = 0; i < 2; ++i) {               // A: 512 chunks, 2/thread
            int ch  = t + i * 256;
            int row = ch >> 3;
            int sl  = ch & 7;
            ra0[i] = *(const float4*)&emb[(size_t)(rb + row) * DD + k0 + sl * 8];
            ra1[i] = *(const float4*)&emb[(size_t)(rb + row) * DD + k0 + sl * 8 + 4];
        }
        #pragma unroll
        for (int i = 0; i < 4; ++i) {               // B: 1024 chunks, 4/thread
            int ch  = t + i * 256;
            int row = ch >> 3;
            int sl  = ch & 7;
            rbv[i] = *(const int4*)&W1t[(size_t)(cb + row) * DD + k0 + sl * 8];
        }
        __syncthreads();
        #pragma unroll
        for (int i = 0; i < 2; ++i) {
            int ch  = t + i * 256;
            int row = ch >> 3;
            int sl  = ch & 7;
            ushort av[8];
            av[0] = f2bf(ra0[i].x); av[1] = f2bf(ra0[i].y);
            av[2] = f2bf(ra0[i].z); av[3] = f2bf(ra0[i].w);
            av[4] = f2bf(ra1[i].x); av[5] = f2bf(ra1[i].y);
            av[6] = f2bf(ra1[i].z); av[7] = f2bf(ra1[i].w);
            *(int4*)&Asm[row * 72 + sl * 8] = *(int4*)av;
        }
        #pragma unroll
        for (int i = 0; i < 4; ++i) {
            int ch  = t + i * 256;
            int row = ch >> 3;
            int sl  = ch & 7;
            *(int4*)&Bsm[row * 72 + sl * 8] = rbv[i];
        }
        __syncthreads();

        #pragma unroll
        for (int kk = 0; kk < 2; ++kk) {
            bf16x8 af[2], bfr[4];
            #pragma unroll
            for (int m = 0; m < 2; ++m)
                af[m] = *(const bf16x8*)&Asm[(wm * 32 + m * 16 + l16) * 72 + kk * 32 + g8];
            #pragma unroll
            for (int n = 0; n < 4; ++n)
                bfr[n] = *(const bf16x8*)&Bsm[(wn * 64 + n * 16 + l16) * 72 + kk * 32 + g8];
            #pragma unroll
            for (int m = 0; m < 2; ++m)
                #pragma unroll
                for (int n = 0; n < 4; ++n)
                    acc[m][n] = __builtin_amdgcn_mfma_f32_16x16x32_bf16(
                        af[m], bfr[n], acc[m][n], 0, 0, 0);
        }
    }

    float bv[4];
    #pragma unroll
    for (int n = 0; n < 4; ++n)
        bv[n] = b1[cb + wn * 64 + n * 16 + l16];

    __syncthreads();
    // stage 64x128 bf16 C tile (16 KB) for coalesced stores
    #pragma unroll
    for (int m = 0; m < 2; ++m)
        #pragma unroll
        for (int n = 0; n < 4; ++n)
            #pragma unroll
            for (int j = 0; j < 4; ++j)
                smem[(wm * 32 + m * 16 + g4 + j) * 128 + wn * 64 + n * 16 + l16] =
                    f2bf(acc[m][n][j] + bv[n]);
    __syncthreads();
    #pragma unroll
    for (int i = 0; i < 4; ++i) {
        int ch  = t + i * 256;              // 1024 chunks of 16 B
        int row = ch >> 4;
        int q   = ch & 15;
        *(int4*)&h1raw[(size_t)(rb + row) * NH1 + cb + q * 8] =
            *(const int4*)&smem[row * 128 + q * 8];
    }
}

// ---------------------------------------------------------------------------
// k1_ln: in-place LN+relu over h1 rows (512 bf16). One wave per row.
__global__ __launch_bounds__(256) void k1_ln(
    ushort* h1, const float* __restrict__ g1, const float* __restrict__ be1)
{
    const int lane = threadIdx.x & 63;
    const int w    = threadIdx.x >> 6;
    const size_t row = (size_t)blockIdx.x * 4 + w;

    ushort* p = h1 + row * NH1 + lane * 8;
    ushort u[8];
    *(int4*)u = *(const int4*)p;
    float x[8];
    float s = 0.f, q = 0.f;
    #pragma unroll
    for (int j = 0; j < 8; ++j) {
        x[j] = bf2f(u[j]);
        s += x[j];
        q += x[j] * x[j];
    }
    #pragma unroll
    for (int off = 32; off; off >>= 1) {
        s += __shfl_xor(s, off);
        q += __shfl_xor(q, off);
    }
    const float mu  = s * (1.f / NH1);
    const float var = q * (1.f / NH1) - mu * mu;
    const float rs  = rsqrtf(var + 1e-5f);

    float gv[8], ev[8];
    *(float4*)&gv[0] = *(const float4*)&g1[lane * 8];
    *(float4*)&gv[4] = *(const float4*)&g1[lane * 8 + 4];
    *(float4*)&ev[0] = *(const float4*)&be1[lane * 8];
    *(float4*)&ev[4] = *(const float4*)&be1[lane * 8 + 4];
    #pragma unroll
    for (int j = 0; j < 8; ++j)
        u[j] = f2bf(fmaxf(fmaf((x[j] - mu) * rs, gv[j], ev[j]), 0.f));
    *(int4*)p = *(int4*)u;
}

// ---------------------------------------------------------------------------
// k2 (MFMA, fused LN+relu): h2 = relu(LN(h1 @ W2 + b2)) stored bf16
__global__ __launch_bounds__(512) void k2_mfma(
    const ushort* __restrict__ h1, const ushort* __restrict__ W2t,
    const float* __restrict__ b2, const float* __restrict__ g2,
    const float* __restrict__ be2, ushort* __restrict__ h2)
{
    __shared__ ushort Asm[64 * 72];     //  9.2 KB
    __shared__ ushort Bsm[256 * 72];    // 36.9 KB
    __shared__ float red[8][64][2];
    __shared__ float stats[64][2];

    const int t    = threadIdx.x;
    const int lane = t & 63;
    const int wid  = t >> 6;
    const int wm   = wid >> 2;          // 0..1
    const int wn   = wid & 3;           // 0..3
    const int l16  = lane & 15;
    const int g8   = (lane >> 4) * 8;
    const int g4   = (lane >> 4) * 4;
    const int rb   = blockIdx.x * 64;

    const int arow = t >> 3, asl = t & 7;   // A: 512 chunks, 1/thread

    f32x4 acc[2][4] = {};

    for (int ks = 0; ks < 8; ++ks) {
        const int k0 = ks * 64;
        int4 ra = *(const int4*)&h1[(size_t)(rb + arow) * NH1 + k0 + asl * 8];
        int4 rbv[4];
        #pragma unroll
        for (int i = 0; i < 4; ++i) {
            int ch = t + i * 512;           // B: 2048 chunks, 4/thread
            int row = ch >> 3, sl = ch & 7;
            rbv[i] = *(const int4*)&W2t[(size_t)row * NH1 + k0 + sl * 8];
        }
        __syncthreads();
        *(int4*)&Asm[arow * 72 + asl * 8] = ra;
        #pragma unroll
        for (int i = 0; i < 4; ++i) {
            int ch = t + i * 512;
            int row = ch >> 3, sl = ch & 7;
            *(int4*)&Bsm[row * 72 + sl * 8] = rbv[i];
        }
        __syncthreads();

        #pragma unroll
        for (int kk = 0; kk < 2; ++kk) {
            bf16x8 af[2], bfr[4];
            #pragma unroll
            for (int m = 0; m < 2; ++m)
                af[m] = *(const bf16x8*)&Asm[(wm * 32 + m * 16 + l16) * 72 + kk * 32 + g8];
            #pragma unroll
            for (int n = 0; n < 4; ++n)
                bfr[n] = *(const bf16x8*)&Bsm[(wn * 64 + n * 16 + l16) * 72 + kk * 32 + g8];
            #pragma unroll
            for (int m = 0; m < 2; ++m)
                #pragma unroll
                for (int n = 0; n < 4; ++n)
                    acc[m][n] = __builtin_amdgcn_mfma_f32_16x16x32_bf16(
                        af[m], bfr[n], acc[m][n], 0, 0, 0);
        }
    }

    float bv[4];
    #pragma unroll
    for (int n = 0; n < 4; ++n) bv[n] = b2[wn * 64 + n * 16 + l16];
    #pragma unroll
    for (int m = 0; m < 2; ++m)
        #pragma unroll
        for (int n = 0; n < 4; ++n)
            #pragma unroll
            for (int j = 0; j < 4; ++j) acc[m][n][j] += bv[n];

    #pragma unroll
    for (int m = 0; m < 2; ++m)
        #pragma unroll
        for (int j = 0; j < 4; ++j) {
            float p = 0.f, q = 0.f;
            #pragma unroll
            for (int n = 0; n < 4; ++n) {
                float v = acc[m][n][j];
                p += v; q += v * v;
            }
            #pragma unroll
            for (int off = 8; off; off >>= 1) {
                p += __shfl_xor(p, off);
                q += __shfl_xor(q, off);
            }
            if (l16 == 0) {
                red[wid][wm * 32 + m * 16 + g4 + j][0] = p;
                red[wid][wm * 32 + m * 16 + g4 + j][1] = q;
            }
        }
    __syncthreads();
    if (t < 64) {
        const int w0 = (t >> 5) * 4;
        float S = 0.f, S2 = 0.f;
        #pragma unroll
        for (int w = 0; w < 4; ++w) { S += red[w0 + w][t][0]; S2 += red[w0 + w][t][1]; }
        float mu  = S  * (1.f / NH2);
        float var = S2 * (1.f / NH2) - mu * mu;
        stats[t][0] = mu;
        stats[t][1] = rsqrtf(var + 1e-5f);
    }
    __syncthreads();

    float gv[4], ev[4];
    #pragma unroll
    for (int n = 0; n < 4; ++n) {
        int col = wn * 64 + n * 16 + l16;
        gv[n] = g2[col]; ev[n] = be2[col];
    }
    ushort* dst = h2 + (size_t)rb * NH2;
    #pragma unroll
    for (int m = 0; m < 2; ++m)
        #pragma unroll
        for (int j = 0; j < 4; ++j) {
            int row = wm * 32 + m * 16 + g4 + j;
            float mu = stats[row][0], rs = stats[row][1];
            #pragma unroll
            for (int n = 0; n < 4; ++n) {
                float val = fmaxf(fmaf((acc[m][n][j] - mu) * rs, gv[n], ev[n]), 0.f);
                dst[(size_t)row * NH2 + wn * 64 + n * 16 + l16] = f2bf(val);
            }
        }
}

// ---------------------------------------------------------------------------
// k3a (MFMA): W_flat(bf16) = h2 @ Wd + bd, packed into the SECOND half of each
// output row's fp32 slot (row*12288B + 6144B). Epilogue staged through LDS.
__global__ __launch_bounds__(256) void k_gemm_wd_mfma(
    const ushort* __restrict__ h2, const ushort* __restrict__ Wdt,
    const float* __restrict__ bd, ushort* __restrict__ outw)
{
    __shared__ ushort smem[2 * 128 * 72];   // Asm | Bsm; reused for C-stage
    ushort* Asm = smem;
    ushort* Bsm = smem + 128 * 72;

    const int t    = threadIdx.x;
    const int lane = t & 63;
    const int wid  = t >> 6;
    const int wm   = wid >> 1;
    const int wn   = wid & 1;
    const int l16  = lane & 15;
    const int g8   = (lane >> 4) * 8;
    const int g4   = (lane >> 4) * 4;

    const int rb = blockIdx.y * 128;
    const int cb = blockIdx.x * 128;

    f32x4 acc[4][4] = {};

    for (int ks = 0; ks < 4; ++ks) {
        const int k0 = ks * 64;
        int4 ra[4], rbv[4];
        #pragma unroll
        for (int i = 0; i < 4; ++i) {
            int ch  = t + i * 256;
            int row = ch >> 3;
            int sl  = ch & 7;
            ra[i]  = *(const int4*)&h2 [(size_t)(rb + row) * NH2 + k0 + sl * 8];
            rbv[i] = *(const int4*)&Wdt[(size_t)(cb + row) * NH2 + k0 + sl * 8];
        }
        __syncthreads();
        #pragma unroll
        for (int i = 0; i < 4; ++i) {
            int ch  = t + i * 256;
            int row = ch >> 3;
            int sl  = ch & 7;
            *(int4*)&Asm[row * 72 + sl * 8] = ra[i];
            *(int4*)&Bsm[row * 72 + sl * 8] = rbv[i];
        }
        __syncthreads();

        #pragma unroll
        for (int kk = 0; kk < 2; ++kk) {
            bf16x8 af[4], bfr[4];
            #pragma unroll
            for (int m = 0; m < 4; ++m)
                af[m] = *(const bf16x8*)&Asm[(wm * 64 + m * 16 + l16) * 72 + kk * 32 + g8];
            #pragma unroll
            for (int n = 0; n < 4; ++n)
                bfr[n] = *(const bf16x8*)&Bsm[(wn * 64 + n * 16 + l16) * 72 + kk * 32 + g8];
            #pragma unroll
            for (int m = 0; m < 4; ++m)
                #pragma unroll
                for (int n = 0; n < 4; ++n)
                    acc[m][n] = __builtin_amdgcn_mfma_f32_16x16x32_bf16(
                        af[m], bfr[n], acc[m][n], 0, 0, 0);
        }
    }

    float bv[4];
    #pragma unroll
    for (int n = 0; n < 4; ++n)
        bv[n] = bd[cb + wn * 64 + n * 16 + l16];

    __syncthreads();
    #pragma unroll
    for (int m = 0; m < 4; ++m)
        #pragma unroll
        for (int n = 0; n < 4; ++n)
            #pragma unroll
            for (int j = 0; j < 4; ++j)
                smem[(wm * 64 + m * 16 + g4 + j) * 128 + wn * 64 + n * 16 + l16] =
                    f2bf(acc[m][n][j] + bv[n]);
    __syncthreads();
    #pragma unroll
    for (int i = 0; i < 8; ++i) {
        int ch  = t + i * 256;
        int row = ch >> 4;
        int q   = ch & 15;
        *(int4*)&outw[(size_t)(rb + row) * 6144 + 3072 + cb + q * 8] =
            *(const int4*)&smem[row * 128 + q * 8];
    }
}

// ---------------------------------------------------------------------------
// k_attn_gemm: scores = h2 @ Wa + ba (raw fp32, pre-softmax) -> ws.
// Pure wd-structure GEMM: 128x128 tile, grid 768 blocks (3/CU). Softmax moved
// into k_gs (wave-local). fp32 C staged via LDS (stride 132: conflict-free).
__global__ __launch_bounds__(256) void k_attn_gemm(
    const ushort* __restrict__ h2, const ushort* __restrict__ Wat,
    const float* __restrict__ ba, float* __restrict__ scores)
{
    __shared__ ushort smem[2 * 128 * 72];   // 36.9 KB; f32 stage [64][132]=33.8 KB
    ushort* Asm = smem;
    ushort* Bsm = smem + 128 * 72;

    const int t    = threadIdx.x;
    const int lane = t & 63;
    const int wid  = t >> 6;
    const int wm   = wid >> 1;
    const int wn   = wid & 1;
    const int l16  = lane & 15;
    const int g8   = (lane >> 4) * 8;
    const int g4   = (lane >> 4) * 4;

    const int rb = blockIdx.y * 128;
    const int cb = blockIdx.x * 128;    // over DD=768

    f32x4 acc[4][4] = {};

    for (int ks = 0; ks < 4; ++ks) {
        const int k0 = ks * 64;
        int4 ra[4], rbv[4];
        #pragma unroll
        for (int i = 0; i < 4; ++i) {
            int ch  = t + i * 256;
            int row = ch >> 3;
            int sl  = ch & 7;
            ra[i]  = *(const int4*)&h2 [(size_t)(rb + row) * NH2 + k0 + sl * 8];
            rbv[i] = *(const int4*)&Wat[(size_t)(cb + row) * NH2 + k0 + sl * 8];
        }
        __syncthreads();
        #pragma unroll
        for (int i = 0; i < 4; ++i) {
            int ch  = t + i * 256;
            int row = ch >> 3;
            int sl  = ch & 7;
            *(int4*)&Asm[row * 72 + sl * 8] = ra[i];
            *(int4*)&Bsm[row * 72 + sl * 8] = rbv[i];
        }
        __syncthreads();

        #pragma unroll
        for (int kk = 0; kk < 2; ++kk) {
            bf16x8 af[4], bfr[4];
            #pragma unroll
            for (int m = 0; m < 4; ++m)
                af[m] = *(const bf16x8*)&Asm[(wm * 64 + m * 16 + l16) * 72 + kk * 32 + g8];
            #pragma unroll
            for (int n = 0; n < 4; ++n)
                bfr[n] = *(const bf16x8*)&Bsm[(wn * 64 + n * 16 + l16) * 72 + kk * 32 + g8];
            #pragma unroll
            for (int m = 0; m < 4; ++m)
                #pragma unroll
                for (int n = 0; n < 4; ++n)
                    acc[m][n] = __builtin_amdgcn_mfma_f32_16x16x32_bf16(
                        af[m], bfr[n], acc[m][n], 0, 0, 0);
        }
    }

    float bv[4];
    #pragma unroll
    for (int n = 0; n < 4; ++n)
        bv[n] = ba[cb + wn * 64 + n * 16 + l16];

    float* stage = (float*)smem;
    #pragma unroll
    for (int h = 0; h < 2; ++h) {
        __syncthreads();    // K-loop LDS / previous pass reads done
        if (wm == h) {
            #pragma unroll
            for (int m = 0; m < 4; ++m)
                #pragma unroll
                for (int n = 0; n < 4; ++n)
                    #pragma unroll
                    for (int j = 0; j < 4; ++j)
                        stage[(m * 16 + g4 + j) * 132 + wn * 64 + n * 16 + l16] =
                            acc[m][n][j] + bv[n];
        }
        __syncthreads();
        #pragma unroll
        for (int i = 0; i < 8; ++i) {
            int ch  = t + i * 256;          // 2048 chunks of 16 B (64 rows x 512 B)
            int row = ch >> 5;
            int q   = ch & 31;
            *(float4*)&scores[(size_t)(rb + h * 64 + row) * DD + cb + q * 4] =
                *(const float4*)&stage[row * 132 + q * 4];
        }
    }
}

// ---------------------------------------------------------------------------
// k4: per row: softmax(scores) -> attn (write to out), W = Wflat_bf16 * attn,
// modified Gram-Schmidt, normalize. One wave per row.
__global__ __launch_bounds__(256) void k_gs(
    const float* __restrict__ scores, float* __restrict__ out)
{
    const int wid  = threadIdx.x >> 6;
    const int lane = threadIdx.x & 63;
    const size_t row = (size_t)blockIdx.x * 4 + wid;

    float* Wf = out + row * (KK * DD);
    const ushort* wsrc = (const ushort*)out + row * 6144 + 3072;
    float* attn_out = out + (size_t)BSZ * (KK * DD) + row * DD;
    const float* sc = scores + row * DD;

    // softmax over the row (12 values/lane x 64 lanes = 768)
    float a[12];
    #pragma unroll
    for (int k = 0; k < 3; ++k) {
        float4 av = *(const float4*)&sc[lane * 4 + 256 * k];
        a[k * 4 + 0] = av.x; a[k * 4 + 1] = av.y;
        a[k * 4 + 2] = av.z; a[k * 4 + 3] = av.w;
    }
    float mx = a[0];
    #pragma unroll
    for (int j = 1; j < 12; ++j) mx = fmaxf(mx, a[j]);
    #pragma unroll
    for (int off = 32; off; off >>= 1) mx = fmaxf(mx, __shfl_xor(mx, off));
    float s = 0.f;
    #pragma unroll
    for (int j = 0; j < 12; ++j) { a[j] = __expf(a[j] - mx); s += a[j]; }
    #pragma unroll
    for (int off = 32; off; off >>= 1) s += __shfl_xor(s, off);
    const float inv = 1.f / s;
    #pragma unroll
    for (int j = 0; j < 12; ++j) a[j] *= inv;
    #pragma unroll
    for (int k = 0; k < 3; ++k) {
        float4 av;
        av.x = a[k * 4 + 0]; av.y = a[k * 4 + 1];
        av.z = a[k * 4 + 2]; av.w = a[k * 4 + 3];
        *(float4*)&attn_out[lane * 4 + 256 * k] = av;
    }

    float w[4][12];
    #pragma unroll
    for (int i = 0; i < 4; ++i) {
        #pragma unroll
        for (int k = 0; k < 3; ++k) {
            ushort4 uv = *(const ushort4*)&wsrc[i * DD + lane * 4 + 256 * k];
            w[i][k * 4 + 0] = bf2f(uv.x) * a[k * 4 + 0];
            w[i][k * 4 + 1] = bf2f(uv.y) * a[k * 4 + 1];
            w[i][k * 4 + 2] = bf2f(uv.z) * a[k * 4 + 2];
            w[i][k * 4 + 3] = bf2f(uv.w) * a[k * 4 + 3];
        }
    }
    #pragma unroll
    for (int i = 0; i < 4; ++i) {
        #pragma unroll
        for (int p = 0; p < i; ++p) {
            float s2 = 0.f;
            #pragma unroll
            for (int j = 0; j < 12; ++j) s2 = fmaf(w[i][j], w[p][j], s2);
            #pragma unroll
            for (int off = 32; off; off >>= 1) s2 += __shfl_xor(s2, off);
            #pragma unroll
            for (int j = 0; j < 12; ++j) w[i][j] = fmaf(-s2, w[p][j], w[i][j]);
        }
        float n2 = 0.f;
        #pragma unroll
        for (int j = 0; j < 12; ++j) n2 = fmaf(w[i][j], w[i][j], n2);
        #pragma unroll
        for (int off = 32; off; off >>= 1) n2 += __shfl_xor(n2, off);
        float invn = 1.f / fmaxf(sqrtf(n2), 1e-12f);
        #pragma unroll
        for (int j = 0; j < 12; ++j) w[i][j] *= invn;
    }
    #pragma unroll
    for (int i = 0; i < 4; ++i) {
        #pragma unroll
        for (int k = 0; k < 3; ++k) {
            float4 wv;
            wv.x = w[i][k * 4 + 0]; wv.y = w[i][k * 4 + 1];
            wv.z = w[i][k * 4 + 2]; wv.w = w[i][k * 4 + 3];
            *(float4*)&Wf[i * DD + lane * 4 + 256 * k] = wv;
        }
    }
}

// ---------------------------------------------------------------------------
extern "C" void kernel_launch(void* const* d_in, const int* in_sizes, int n_in,
                              void* d_out, int out_size, void* d_ws, size_t ws_size,
                              hipStream_t stream)
{
    const float* emb = (const float*)d_in[0];
    const float* W1  = (const float*)d_in[1];
    const float* b1  = (const float*)d_in[2];
    const float* g1  = (const float*)d_in[3];
    const float* be1 = (const float*)d_in[4];
    const float* W2  = (const float*)d_in[5];
    const float* b2  = (const float*)d_in[6];
    const float* g2  = (const float*)d_in[7];
    const float* be2 = (const float*)d_in[8];
    const float* Wd  = (const float*)d_in[9];
    const float* bd  = (const float*)d_in[10];
    const float* Wa  = (const float*)d_in[11];
    const float* ba  = (const float*)d_in[12];

    float* out = (float*)d_out;
    ushort* h1  = (ushort*)d_ws;                 // B*512 bf16 = 16.8 MB
    ushort* h2  = h1 + (size_t)BSZ * NH1;        // B*256 bf16 =  8.4 MB
    ushort* Wdt = h2 + (size_t)BSZ * NH2;        // 3072*256 bf16 = 1.5 MB
    ushort* W1t = Wdt + (size_t)ND * NH2;        // 512*768 bf16 = 0.77 MB
    ushort* W2t = W1t + (size_t)NH1 * DD;        // 256*512 bf16 = 0.25 MB
    ushort* Wat = W2t + (size_t)NH2 * NH1;       // 768*256 bf16 = 0.39 MB
    float* scores = (float*)(Wat + (size_t)DD * NH2);  // B*768 f32 = 50.3 MB
    float* attn = out + (size_t)BSZ * KK * DD;   // attn region of out, B*D

    hipLaunchKernelGGL(k_t_cvt, dim3(NH1 / 32, DD / 32), dim3(256), 0, stream,
                       W1, W1t, DD, NH1);        // W1 (768x512) -> W1t (512x768)
    hipLaunchKernelGGL(k_t_cvt, dim3(NH2 / 32, NH1 / 32), dim3(256), 0, stream,
                       W2, W2t, NH1, NH2);       // W2 (512x256) -> W2t (256x512)
    hipLaunchKernelGGL(k_t_cvt, dim3(ND / 32, NH2 / 32), dim3(256), 0, stream,
                       Wd, Wdt, NH2, ND);        // Wd (256x3072) -> Wdt (3072x256)
    hipLaunchKernelGGL(k_t_cvt, dim3(DD / 32, NH2 / 32), dim3(256), 0, stream,
                       Wa, Wat, NH2, DD);        // Wa (256x768) -> Wat (768x256)
    hipLaunchKernelGGL(k1_gemm, dim3(NH1 / 128, BSZ / 64), dim3(256), 0, stream,
                       emb, W1t, b1, h1);
    hipLaunchKernelGGL(k1_ln, dim3(BSZ / 4), dim3(256), 0, stream,
                       h1, g1, be1);
    hipLaunchKernelGGL(k2_mfma, dim3(BSZ / 64), dim3(512), 0, stream,
                       h1, W2t, b2, g2, be2, h2);
    hipLaunchKernelGGL(k_gemm_wd_mfma, dim3(ND / 128, BSZ / 128), dim3(256), 0, stream,
                       h2, Wdt, bd, (ushort*)out);
    hipLaunchKernelGGL(k_attn_gemm, dim3(DD / 128, BSZ / 128), dim3(256), 0, stream,
                       h2, Wat, ba, scores);
    hipLaunchKernelGGL(k_gs, dim3(BSZ / 4), dim3(256), 0, stream,
                       scores, out);
}

// Round 9
// 353.588 us; speedup vs baseline: 1.0258x; 1.0258x over previous
//
#include <hip/hip_runtime.h>
#include <hip/hip_bf16.h>

#define BSZ 16384
#define DD  768
#define KK  4
#define NH1 512
#define NH2 256
#define ND  (KK * DD)   // 3072

typedef __bf16 bf16x8 __attribute__((ext_vector_type(8)));
typedef float  f32x4  __attribute__((ext_vector_type(4)));

static __device__ __forceinline__ float bf2f(ushort u) {
    union { unsigned int i; float f; } v; v.i = (unsigned int)u << 16; return v.f;
}
static __device__ __forceinline__ ushort f2bf(float f) {
    return __bfloat16_as_ushort(__float2bfloat16(f));
}

// ---------------------------------------------------------------------------
// k_cvt_emb: emb fp32 -> bf16, row-major copy-convert (8 elems/thread/iter)
__global__ __launch_bounds__(256) void k_cvt_emb(
    const float* __restrict__ src, ushort* __restrict__ dst, int n8)
{
    const int stride = gridDim.x * 256;
    for (int i = blockIdx.x * 256 + threadIdx.x; i < n8; i += stride) {
        float4 a = *(const float4*)&src[(size_t)i * 8];
        float4 b = *(const float4*)&src[(size_t)i * 8 + 4];
        ushort u[8];
        u[0] = f2bf(a.x); u[1] = f2bf(a.y); u[2] = f2bf(a.z); u[3] = f2bf(a.w);
        u[4] = f2bf(b.x); u[5] = f2bf(b.y); u[6] = f2bf(b.z); u[7] = f2bf(b.w);
        *(int4*)&dst[(size_t)i * 8] = *(int4*)u;
    }
}

// ---------------------------------------------------------------------------
// k_t_cvt: src (R x C f32) -> dst (C x R bf16)  [generic transpose+convert]
__global__ __launch_bounds__(256) void k_t_cvt(
    const float* __restrict__ src, ushort* __restrict__ dst, int R, int C)
{
    __shared__ float tile[32][33];
    const int rb0 = blockIdx.y * 32;  // src row
    const int cb0 = blockIdx.x * 32;  // src col
    const int t = threadIdx.x;
    const int r = t >> 5, c = t & 31;
    #pragma unroll
    for (int i = 0; i < 4; ++i)
        tile[r + i * 8][c] = src[(size_t)(rb0 + r + i * 8) * C + cb0 + c];
    __syncthreads();
    #pragma unroll
    for (int i = 0; i < 4; ++i)
        dst[(size_t)(cb0 + r + i * 8) * R + rb0 + c] = f2bf(tile[c][r + i * 8]);
}

// ---------------------------------------------------------------------------
// k1_gemm: h1_raw = embb @ W1 + b1 (bf16). Exact wd-kernel structure:
// 128x128 tile, BK=64, 12 K-steps, int4 staging (emb pre-converted to bf16 --
// round-9 change: removes 2x A bytes + 16 cvts/K-step from staging path).
__global__ __launch_bounds__(256) void k1_gemm(
    const ushort* __restrict__ embb, const ushort* __restrict__ W1t,
    const float* __restrict__ b1, ushort* __restrict__ h1raw)
{
    __shared__ ushort smem[2 * 128 * 72];   // Asm | Bsm; reused for C-stage
    ushort* Asm = smem;
    ushort* Bsm = smem + 128 * 72;

    const int t    = threadIdx.x;
    const int lane = t & 63;
    const int wid  = t >> 6;
    const int wm   = wid >> 1;
    const int wn   = wid & 1;
    const int l16  = lane & 15;
    const int g8   = (lane >> 4) * 8;
    const int g4   = (lane >> 4) * 4;

    const int rb = blockIdx.y * 128;    // M tile
    const int cb = blockIdx.x * 128;    // N tile (over NH1=512)

    f32x4 acc[4][4] = {};

    for (int ks = 0; ks < 12; ++ks) {
        const int k0 = ks * 64;
        int4 ra[4], rbv[4];
        #pragma unroll
        for (int i = 0; i < 4; ++i) {
            int ch  = t + i * 256;          // 1024 chunks of 16B per matrix
            int row = ch >> 3;
            int sl  = ch & 7;
            ra[i]  = *(const int4*)&embb[(size_t)(rb + row) * DD + k0 + sl * 8];
            rbv[i] = *(const int4*)&W1t [(size_t)(cb + row) * DD + k0 + sl * 8];
        }
        __syncthreads();
        #pragma unroll
        for (int i = 0; i < 4; ++i) {
            int ch  = t + i * 256;
            int row = ch >> 3;
            int sl  = ch & 7;
            *(int4*)&Asm[row * 72 + sl * 8] = ra[i];
            *(int4*)&Bsm[row * 72 + sl * 8] = rbv[i];
        }
        __syncthreads();

        #pragma unroll
        for (int kk = 0; kk < 2; ++kk) {
            bf16x8 af[4], bfr[4];
            #pragma unroll
            for (int m = 0; m < 4; ++m)
                af[m] = *(const bf16x8*)&Asm[(wm * 64 + m * 16 + l16) * 72 + kk * 32 + g8];
            #pragma unroll
            for (int n = 0; n < 4; ++n)
                bfr[n] = *(const bf16x8*)&Bsm[(wn * 64 + n * 16 + l16) * 72 + kk * 32 + g8];
            #pragma unroll
            for (int m = 0; m < 4; ++m)
                #pragma unroll
                for (int n = 0; n < 4; ++n)
                    acc[m][n] = __builtin_amdgcn_mfma_f32_16x16x32_bf16(
                        af[m], bfr[n], acc[m][n], 0, 0, 0);
        }
    }

    float bv[4];
    #pragma unroll
    for (int n = 0; n < 4; ++n)
        bv[n] = b1[cb + wn * 64 + n * 16 + l16];

    __syncthreads();
    #pragma unroll
    for (int m = 0; m < 4; ++m)
        #pragma unroll
        for (int n = 0; n < 4; ++n)
            #pragma unroll
            for (int j = 0; j < 4; ++j)
                smem[(wm * 64 + m * 16 + g4 + j) * 128 + wn * 64 + n * 16 + l16] =
                    f2bf(acc[m][n][j] + bv[n]);
    __syncthreads();
    #pragma unroll
    for (int i = 0; i < 8; ++i) {
        int ch  = t + i * 256;              // 2048 chunks of 16 B
        int row = ch >> 4;
        int q   = ch & 15;
        *(int4*)&h1raw[(size_t)(rb + row) * NH1 + cb + q * 8] =
            *(const int4*)&smem[row * 128 + q * 8];
    }
}

// ---------------------------------------------------------------------------
// k1_ln: in-place LN+relu over h1 rows (512 bf16). One wave per row.
__global__ __launch_bounds__(256) void k1_ln(
    ushort* h1, const float* __restrict__ g1, const float* __restrict__ be1)
{
    const int lane = threadIdx.x & 63;
    const int w    = threadIdx.x >> 6;
    const size_t row = (size_t)blockIdx.x * 4 + w;

    ushort* p = h1 + row * NH1 + lane * 8;
    ushort u[8];
    *(int4*)u = *(const int4*)p;
    float x[8];
    float s = 0.f, q = 0.f;
    #pragma unroll
    for (int j = 0; j < 8; ++j) {
        x[j] = bf2f(u[j]);
        s += x[j];
        q += x[j] * x[j];
    }
    #pragma unroll
    for (int off = 32; off; off >>= 1) {
        s += __shfl_xor(s, off);
        q += __shfl_xor(q, off);
    }
    const float mu  = s * (1.f / NH1);
    const float var = q * (1.f / NH1) - mu * mu;
    const float rs  = rsqrtf(var + 1e-5f);

    float gv[8], ev[8];
    *(float4*)&gv[0] = *(const float4*)&g1[lane * 8];
    *(float4*)&gv[4] = *(const float4*)&g1[lane * 8 + 4];
    *(float4*)&ev[0] = *(const float4*)&be1[lane * 8];
    *(float4*)&ev[4] = *(const float4*)&be1[lane * 8 + 4];
    #pragma unroll
    for (int j = 0; j < 8; ++j)
        u[j] = f2bf(fmaxf(fmaf((x[j] - mu) * rs, gv[j], ev[j]), 0.f));
    *(int4*)p = *(int4*)u;
}

// ---------------------------------------------------------------------------
// k2 (MFMA, fused LN+relu): h2 = relu(LN(h1 @ W2 + b2)) stored bf16
__global__ __launch_bounds__(512) void k2_mfma(
    const ushort* __restrict__ h1, const ushort* __restrict__ W2t,
    const float* __restrict__ b2, const float* __restrict__ g2,
    const float* __restrict__ be2, ushort* __restrict__ h2)
{
    __shared__ ushort Asm[64 * 72];     //  9.2 KB
    __shared__ ushort Bsm[256 * 72];    // 36.9 KB
    __shared__ float red[8][64][2];
    __shared__ float stats[64][2];

    const int t    = threadIdx.x;
    const int lane = t & 63;
    const int wid  = t >> 6;
    const int wm   = wid >> 2;          // 0..1
    const int wn   = wid & 3;           // 0..3
    const int l16  = lane & 15;
    const int g8   = (lane >> 4) * 8;
    const int g4   = (lane >> 4) * 4;
    const int rb   = blockIdx.x * 64;

    const int arow = t >> 3, asl = t & 7;   // A: 512 chunks, 1/thread

    f32x4 acc[2][4] = {};

    for (int ks = 0; ks < 8; ++ks) {
        const int k0 = ks * 64;
        int4 ra = *(const int4*)&h1[(size_t)(rb + arow) * NH1 + k0 + asl * 8];
        int4 rbv[4];
        #pragma unroll
        for (int i = 0; i < 4; ++i) {
            int ch = t + i * 512;           // B: 2048 chunks, 4/thread
            int row = ch >> 3, sl = ch & 7;
            rbv[i] = *(const int4*)&W2t[(size_t)row * NH1 + k0 + sl * 8];
        }
        __syncthreads();
        *(int4*)&Asm[arow * 72 + asl * 8] = ra;
        #pragma unroll
        for (int i = 0; i < 4; ++i) {
            int ch = t + i * 512;
            int row = ch >> 3, sl = ch & 7;
            *(int4*)&Bsm[row * 72 + sl * 8] = rbv[i];
        }
        __syncthreads();

        #pragma unroll
        for (int kk = 0; kk < 2; ++kk) {
            bf16x8 af[2], bfr[4];
            #pragma unroll
            for (int m = 0; m < 2; ++m)
                af[m] = *(const bf16x8*)&Asm[(wm * 32 + m * 16 + l16) * 72 + kk * 32 + g8];
            #pragma unroll
            for (int n = 0; n < 4; ++n)
                bfr[n] = *(const bf16x8*)&Bsm[(wn * 64 + n * 16 + l16) * 72 + kk * 32 + g8];
            #pragma unroll
            for (int m = 0; m < 2; ++m)
                #pragma unroll
                for (int n = 0; n < 4; ++n)
                    acc[m][n] = __builtin_amdgcn_mfma_f32_16x16x32_bf16(
                        af[m], bfr[n], acc[m][n], 0, 0, 0);
        }
    }

    float bv[4];
    #pragma unroll
    for (int n = 0; n < 4; ++n) bv[n] = b2[wn * 64 + n * 16 + l16];
    #pragma unroll
    for (int m = 0; m < 2; ++m)
        #pragma unroll
        for (int n = 0; n < 4; ++n)
            #pragma unroll
            for (int j = 0; j < 4; ++j) acc[m][n][j] += bv[n];

    #pragma unroll
    for (int m = 0; m < 2; ++m)
        #pragma unroll
        for (int j = 0; j < 4; ++j) {
            float p = 0.f, q = 0.f;
            #pragma unroll
            for (int n = 0; n < 4; ++n) {
                float v = acc[m][n][j];
                p += v; q += v * v;
            }
            #pragma unroll
            for (int off = 8; off; off >>= 1) {
                p += __shfl_xor(p, off);
                q += __shfl_xor(q, off);
            }
            if (l16 == 0) {
                red[wid][wm * 32 + m * 16 + g4 + j][0] = p;
                red[wid][wm * 32 + m * 16 + g4 + j][1] = q;
            }
        }
    __syncthreads();
    if (t < 64) {
        const int w0 = (t >> 5) * 4;
        float S = 0.f, S2 = 0.f;
        #pragma unroll
        for (int w = 0; w < 4; ++w) { S += red[w0 + w][t][0]; S2 += red[w0 + w][t][1]; }
        float mu  = S  * (1.f / NH2);
        float var = S2 * (1.f / NH2) - mu * mu;
        stats[t][0] = mu;
        stats[t][1] = rsqrtf(var + 1e-5f);
    }
    __syncthreads();

    float gv[4], ev[4];
    #pragma unroll
    for (int n = 0; n < 4; ++n) {
        int col = wn * 64 + n * 16 + l16;
        gv[n] = g2[col]; ev[n] = be2[col];
    }
    ushort* dst = h2 + (size_t)rb * NH2;
    #pragma unroll
    for (int m = 0; m < 2; ++m)
        #pragma unroll
        for (int j = 0; j < 4; ++j) {
            int row = wm * 32 + m * 16 + g4 + j;
            float mu = stats[row][0], rs = stats[row][1];
            #pragma unroll
            for (int n = 0; n < 4; ++n) {
                float val = fmaxf(fmaf((acc[m][n][j] - mu) * rs, gv[n], ev[n]), 0.f);
                dst[(size_t)row * NH2 + wn * 64 + n * 16 + l16] = f2bf(val);
            }
        }
}

// ---------------------------------------------------------------------------
// k3a (MFMA): W_flat(bf16) = h2 @ Wd + bd, packed into the SECOND half of each
// output row's fp32 slot (row*12288B + 6144B). Epilogue staged through LDS.
__global__ __launch_bounds__(256) void k_gemm_wd_mfma(
    const ushort* __restrict__ h2, const ushort* __restrict__ Wdt,
    const float* __restrict__ bd, ushort* __restrict__ outw)
{
    __shared__ ushort smem[2 * 128 * 72];   // Asm | Bsm; reused for C-stage
    ushort* Asm = smem;
    ushort* Bsm = smem + 128 * 72;

    const int t    = threadIdx.x;
    const int lane = t & 63;
    const int wid  = t >> 6;
    const int wm   = wid >> 1;
    const int wn   = wid & 1;
    const int l16  = lane & 15;
    const int g8   = (lane >> 4) * 8;
    const int g4   = (lane >> 4) * 4;

    const int rb = blockIdx.y * 128;
    const int cb = blockIdx.x * 128;

    f32x4 acc[4][4] = {};

    for (int ks = 0; ks < 4; ++ks) {
        const int k0 = ks * 64;
        int4 ra[4], rbv[4];
        #pragma unroll
        for (int i = 0; i < 4; ++i) {
            int ch  = t + i * 256;
            int row = ch >> 3;
            int sl  = ch & 7;
            ra[i]  = *(const int4*)&h2 [(size_t)(rb + row) * NH2 + k0 + sl * 8];
            rbv[i] = *(const int4*)&Wdt[(size_t)(cb + row) * NH2 + k0 + sl * 8];
        }
        __syncthreads();
        #pragma unroll
        for (int i = 0; i < 4; ++i) {
            int ch  = t + i * 256;
            int row = ch >> 3;
            int sl  = ch & 7;
            *(int4*)&Asm[row * 72 + sl * 8] = ra[i];
            *(int4*)&Bsm[row * 72 + sl * 8] = rbv[i];
        }
        __syncthreads();

        #pragma unroll
        for (int kk = 0; kk < 2; ++kk) {
            bf16x8 af[4], bfr[4];
            #pragma unroll
            for (int m = 0; m < 4; ++m)
                af[m] = *(const bf16x8*)&Asm[(wm * 64 + m * 16 + l16) * 72 + kk * 32 + g8];
            #pragma unroll
            for (int n = 0; n < 4; ++n)
                bfr[n] = *(const bf16x8*)&Bsm[(wn * 64 + n * 16 + l16) * 72 + kk * 32 + g8];
            #pragma unroll
            for (int m = 0; m < 4; ++m)
                #pragma unroll
                for (int n = 0; n < 4; ++n)
                    acc[m][n] = __builtin_amdgcn_mfma_f32_16x16x32_bf16(
                        af[m], bfr[n], acc[m][n], 0, 0, 0);
        }
    }

    float bv[4];
    #pragma unroll
    for (int n = 0; n < 4; ++n)
        bv[n] = bd[cb + wn * 64 + n * 16 + l16];

    __syncthreads();
    #pragma unroll
    for (int m = 0; m < 4; ++m)
        #pragma unroll
        for (int n = 0; n < 4; ++n)
            #pragma unroll
            for (int j = 0; j < 4; ++j)
                smem[(wm * 64 + m * 16 + g4 + j) * 128 + wn * 64 + n * 16 + l16] =
                    f2bf(acc[m][n][j] + bv[n]);
    __syncthreads();
    #pragma unroll
    for (int i = 0; i < 8; ++i) {
        int ch  = t + i * 256;
        int row = ch >> 4;
        int q   = ch & 15;
        *(int4*)&outw[(size_t)(rb + row) * 6144 + 3072 + cb + q * 8] =
            *(const int4*)&smem[row * 128 + q * 8];
    }
}

// ---------------------------------------------------------------------------
// k3b (MFMA, fused softmax): attn = softmax(h2 @ Wa + ba)  [round-7 version]
__global__ __launch_bounds__(512) void k_attn_mfma(
    const ushort* __restrict__ h2, const ushort* __restrict__ Wat,
    const float* __restrict__ ba, float* __restrict__ attn)
{
    __shared__ ushort Asm[64 * 72];      //   9.2 KB
    __shared__ ushort Bsm[768 * 72];     // 110.6 KB (reused as f32 stage [32][776])
    __shared__ float red[8][64];
    __shared__ float stats[64];

    const int t    = threadIdx.x;
    const int lane = t & 63;
    const int wid  = t >> 6;
    const int wm   = wid >> 2;          // 0..1
    const int wn   = wid & 3;           // 0..3
    const int l16  = lane & 15;
    const int g8   = (lane >> 4) * 8;
    const int g4   = (lane >> 4) * 4;
    const int rb   = blockIdx.x * 64;

    const int arow = t >> 3, asl = t & 7;

    f32x4 acc[2][12] = {};

    for (int ks = 0; ks < 4; ++ks) {
        const int k0 = ks * 64;
        int4 ra = *(const int4*)&h2[(size_t)(rb + arow) * NH2 + k0 + asl * 8];
        int4 rbv[12];
        #pragma unroll
        for (int i = 0; i < 12; ++i) {
            int ch = t + i * 512;           // B: 6144 chunks, 12/thread
            int row = ch >> 3, sl = ch & 7;
            rbv[i] = *(const int4*)&Wat[(size_t)row * NH2 + k0 + sl * 8];
        }
        __syncthreads();
        *(int4*)&Asm[arow * 72 + asl * 8] = ra;
        #pragma unroll
        for (int i = 0; i < 12; ++i) {
            int ch = t + i * 512;
            int row = ch >> 3, sl = ch & 7;
            *(int4*)&Bsm[row * 72 + sl * 8] = rbv[i];
        }
        __syncthreads();

        #pragma unroll
        for (int kk = 0; kk < 2; ++kk) {
            bf16x8 af[2], bfr[12];
            #pragma unroll
            for (int m = 0; m < 2; ++m)
                af[m] = *(const bf16x8*)&Asm[(wm * 32 + m * 16 + l16) * 72 + kk * 32 + g8];
            #pragma unroll
            for (int n = 0; n < 12; ++n)
                bfr[n] = *(const bf16x8*)&Bsm[(wn * 192 + n * 16 + l16) * 72 + kk * 32 + g8];
            #pragma unroll
            for (int m = 0; m < 2; ++m)
                #pragma unroll
                for (int n = 0; n < 12; ++n)
                    acc[m][n] = __builtin_amdgcn_mfma_f32_16x16x32_bf16(
                        af[m], bfr[n], acc[m][n], 0, 0, 0);
        }
    }

    // bias
    float bb[12];
    #pragma unroll
    for (int n = 0; n < 12; ++n) bb[n] = ba[wn * 192 + n * 16 + l16];
    #pragma unroll
    for (int m = 0; m < 2; ++m)
        #pragma unroll
        for (int n = 0; n < 12; ++n)
            #pragma unroll
            for (int j = 0; j < 4; ++j) acc[m][n][j] += bb[n];

    // row max
    #pragma unroll
    for (int m = 0; m < 2; ++m)
        #pragma unroll
        for (int j = 0; j < 4; ++j) {
            float p = acc[m][0][j];
            #pragma unroll
            for (int n = 1; n < 12; ++n) p = fmaxf(p, acc[m][n][j]);
            #pragma unroll
            for (int off = 8; off; off >>= 1) p = fmaxf(p, __shfl_xor(p, off));
            if (l16 == 0) red[wid][wm * 32 + m * 16 + g4 + j] = p;
        }
    __syncthreads();
    if (t < 64) {
        const int w0 = (t >> 5) * 4;
        stats[t] = fmaxf(fmaxf(red[w0][t], red[w0 + 1][t]),
                         fmaxf(red[w0 + 2][t], red[w0 + 3][t]));
    }
    __syncthreads();
    // exp + row sum
    #pragma unroll
    for (int m = 0; m < 2; ++m)
        #pragma unroll
        for (int j = 0; j < 4; ++j) {
            float M = stats[wm * 32 + m * 16 + g4 + j];
            float s = 0.f;
            #pragma unroll
            for (int n = 0; n < 12; ++n) {
                acc[m][n][j] = __expf(acc[m][n][j] - M);
                s += acc[m][n][j];
            }
            #pragma unroll
            for (int off = 8; off; off >>= 1) s += __shfl_xor(s, off);
            if (l16 == 0) red[wid][wm * 32 + m * 16 + g4 + j] = s;
        }
    __syncthreads();
    if (t < 64) {
        const int w0 = (t >> 5) * 4;
        stats[t] = 1.f / (red[w0][t] + red[w0 + 1][t] + red[w0 + 2][t] + red[w0 + 3][t]);
    }
    __syncthreads();

    // staged fp32 output, two 32-row passes (stride 776 floats: conflict-free)
    float* stage = (float*)Bsm;
    #pragma unroll
    for (int h = 0; h < 2; ++h) {
        if (wm == h) {
            #pragma unroll
            for (int m = 0; m < 2; ++m)
                #pragma unroll
                for (int j = 0; j < 4; ++j) {
                    const int r = m * 16 + g4 + j;
                    const float inv = stats[h * 32 + r];
                    #pragma unroll
                    for (int n = 0; n < 12; ++n)
                        stage[r * 776 + wn * 192 + n * 16 + l16] = acc[m][n][j] * inv;
                }
        }
        __syncthreads();
        #pragma unroll
        for (int i = 0; i < 12; ++i) {
            int ch  = t + i * 512;          // 6144 chunks of 16 B
            int row = ch / 192;
            int q   = ch - row * 192;
            *(float4*)&attn[(size_t)(rb + h * 32 + row) * DD + q * 4] =
                *(const float4*)&stage[row * 776 + q * 4];
        }
        __syncthreads();
    }
}

// ---------------------------------------------------------------------------
// k4: per row: W = Wflat_bf16 * attn; modified Gram-Schmidt; normalize.
__global__ __launch_bounds__(256) void k_gs(float* __restrict__ out)
{
    const int wid  = threadIdx.x >> 6;
    const int lane = threadIdx.x & 63;
    const size_t row = (size_t)blockIdx.x * 4 + wid;

    float* Wf = out + row * (KK * DD);
    const ushort* wsrc = (const ushort*)out + row * 6144 + 3072;
    const float* at = out + (size_t)BSZ * (KK * DD) + row * DD;

    float a[12];
    #pragma unroll
    for (int k = 0; k < 3; ++k) {
        float4 av = *(const float4*)&at[lane * 4 + 256 * k];
        a[k * 4 + 0] = av.x; a[k * 4 + 1] = av.y;
        a[k * 4 + 2] = av.z; a[k * 4 + 3] = av.w;
    }
    float w[4][12];
    #pragma unroll
    for (int i = 0; i < 4; ++i) {
        #pragma unroll
        for (int k = 0; k < 3; ++k) {
            ushort4 uv = *(const ushort4*)&wsrc[i * DD + lane * 4 + 256 * k];
            w[i][k * 4 + 0] = bf2f(uv.x) * a[k * 4 + 0];
            w[i][k * 4 + 1] = bf2f(uv.y) * a[k * 4 + 1];
            w[i][k * 4 + 2] = bf2f(uv.z) * a[k * 4 + 2];
            w[i][k * 4 + 3] = bf2f(uv.w) * a[k * 4 + 3];
        }
    }
    #pragma unroll
    for (int i = 0; i < 4; ++i) {
        #pragma unroll
        for (int p = 0; p < i; ++p) {
            float s = 0.f;
            #pragma unroll
            for (int j = 0; j < 12; ++j) s = fmaf(w[i][j], w[p][j], s);
            #pragma unroll
            for (int off = 32; off; off >>= 1) s += __shfl_xor(s, off);
            #pragma unroll
            for (int j = 0; j < 12; ++j) w[i][j] = fmaf(-s, w[p][j], w[i][j]);
        }
        float n2 = 0.f;
        #pragma unroll
        for (int j = 0; j < 12; ++j) n2 = fmaf(w[i][j], w[i][j], n2);
        #pragma unroll
        for (int off = 32; off; off >>= 1) n2 += __shfl_xor(n2, off);
        float inv = 1.f / fmaxf(sqrtf(n2), 1e-12f);
        #pragma unroll
        for (int j = 0; j < 12; ++j) w[i][j] *= inv;
    }
    #pragma unroll
    for (int i = 0; i < 4; ++i) {
        #pragma unroll
        for (int k = 0; k < 3; ++k) {
            float4 wv;
            wv.x = w[i][k * 4 + 0]; wv.y = w[i][k * 4 + 1];
            wv.z = w[i][k * 4 + 2]; wv.w = w[i][k * 4 + 3];
            *(float4*)&Wf[i * DD + lane * 4 + 256 * k] = wv;
        }
    }
}

// ---------------------------------------------------------------------------
extern "C" void kernel_launch(void* const* d_in, const int* in_sizes, int n_in,
                              void* d_out, int out_size, void* d_ws, size_t ws_size,
                              hipStream_t stream)
{
    const float* emb = (const float*)d_in[0];
    const float* W1  = (const float*)d_in[1];
    const float* b1  = (const float*)d_in[2];
    const float* g1  = (const float*)d_in[3];
    const float* be1 = (const float*)d_in[4];
    const float* W2  = (const float*)d_in[5];
    const float* b2  = (const float*)d_in[6];
    const float* g2  = (const float*)d_in[7];
    const float* be2 = (const float*)d_in[8];
    const float* Wd  = (const float*)d_in[9];
    const float* bd  = (const float*)d_in[10];
    const float* Wa  = (const float*)d_in[11];
    const float* ba  = (const float*)d_in[12];

    float* out = (float*)d_out;
    ushort* h1   = (ushort*)d_ws;                // B*512 bf16 = 16.8 MB
    ushort* h2   = h1 + (size_t)BSZ * NH1;       // B*256 bf16 =  8.4 MB
    ushort* Wdt  = h2 + (size_t)BSZ * NH2;       // 3072*256 bf16 = 1.5 MB
    ushort* W1t  = Wdt + (size_t)ND * NH2;       // 512*768 bf16 = 0.77 MB
    ushort* W2t  = W1t + (size_t)NH1 * DD;       // 256*512 bf16 = 0.25 MB
    ushort* Wat  = W2t + (size_t)NH2 * NH1;      // 768*256 bf16 = 0.39 MB
    ushort* embb = Wat + (size_t)DD * NH2;       // B*768 bf16 = 25.2 MB
    float* attn = out + (size_t)BSZ * KK * DD;   // attn region of out, B*D

    hipLaunchKernelGGL(k_cvt_emb, dim3(2048), dim3(256), 0, stream,
                       emb, embb, BSZ * DD / 8);
    hipLaunchKernelGGL(k_t_cvt, dim3(NH1 / 32, DD / 32), dim3(256), 0, stream,
                       W1, W1t, DD, NH1);        // W1 (768x512) -> W1t (512x768)
    hipLaunchKernelGGL(k_t_cvt, dim3(NH2 / 32, NH1 / 32), dim3(256), 0, stream,
                       W2, W2t, NH1, NH2);       // W2 (512x256) -> W2t (256x512)
    hipLaunchKernelGGL(k_t_cvt, dim3(ND / 32, NH2 / 32), dim3(256), 0, stream,
                       Wd, Wdt, NH2, ND);        // Wd (256x3072) -> Wdt (3072x256)
    hipLaunchKernelGGL(k_t_cvt, dim3(DD / 32, NH2 / 32), dim3(256), 0, stream,
                       Wa, Wat, NH2, DD);        // Wa (256x768) -> Wat (768x256)
    hipLaunchKernelGGL(k1_gemm, dim3(NH1 / 128, BSZ / 128), dim3(256), 0, stream,
                       embb, W1t, b1, h1);
    hipLaunchKernelGGL(k1_ln, dim3(BSZ / 4), dim3(256), 0, stream,
                       h1, g1, be1);
    hipLaunchKernelGGL(k2_mfma, dim3(BSZ / 64), dim3(512), 0, stream,
                       h1, W2t, b2, g2, be2, h2);
    hipLaunchKernelGGL(k_gemm_wd_mfma, dim3(ND / 128, BSZ / 128), dim3(256), 0, stream,
                       h2, Wdt, bd, (ushort*)out);
    hipLaunchKernelGGL(k_attn_mfma, dim3(BSZ / 64), dim3(512), 0, stream,
                       h2, Wat, ba, attn);
    hipLaunchKernelGGL(k_gs, dim3(BSZ / 4), dim3(256), 0, stream, out);
}

// Round 10
// 230.300 us; speedup vs baseline: 1.5749x; 1.5353x over previous
//
#include <hip/hip_runtime.h>
#include <hip/hip_bf16.h>

#define BSZ 16384
#define DD  768
#define KK  4
#define NH1 512
#define NH2 256
#define ND  (KK * DD)   // 3072

typedef __bf16 bf16x8 __attribute__((ext_vector_type(8)));
typedef float  f32x4  __attribute__((ext_vector_type(4)));

static __device__ __forceinline__ float bf2f(ushort u) {
    union { unsigned int i; float f; } v; v.i = (unsigned int)u << 16; return v.f;
}
static __device__ __forceinline__ ushort f2bf(float f) {
    return __bfloat16_as_ushort(__float2bfloat16(f));
}
// async global->LDS, 16B per lane; LDS dest = uniform base + lane*16
static __device__ __forceinline__ void gload_lds16(const void* g, void* l) {
    __builtin_amdgcn_global_load_lds(
        (const __attribute__((address_space(1))) void*)g,
        (__attribute__((address_space(3))) void*)l, 16, 0, 0);
}

// ---------------------------------------------------------------------------
// k_cvt_emb: emb fp32 -> bf16, row-major copy-convert (8 elems/thread/iter)
__global__ __launch_bounds__(256) void k_cvt_emb(
    const float* __restrict__ src, ushort* __restrict__ dst, int n8)
{
    const int stride = gridDim.x * 256;
    for (int i = blockIdx.x * 256 + threadIdx.x; i < n8; i += stride) {
        float4 a = *(const float4*)&src[(size_t)i * 8];
        float4 b = *(const float4*)&src[(size_t)i * 8 + 4];
        ushort u[8];
        u[0] = f2bf(a.x); u[1] = f2bf(a.y); u[2] = f2bf(a.z); u[3] = f2bf(a.w);
        u[4] = f2bf(b.x); u[5] = f2bf(b.y); u[6] = f2bf(b.z); u[7] = f2bf(b.w);
        *(int4*)&dst[(size_t)i * 8] = *(int4*)u;
    }
}

// ---------------------------------------------------------------------------
// k_t_cvt: src (R x C f32) -> dst (C x R bf16)  [generic transpose+convert]
__global__ __launch_bounds__(256) void k_t_cvt(
    const float* __restrict__ src, ushort* __restrict__ dst, int R, int C)
{
    __shared__ float tile[32][33];
    const int rb0 = blockIdx.y * 32;  // src row
    const int cb0 = blockIdx.x * 32;  // src col
    const int t = threadIdx.x;
    const int r = t >> 5, c = t & 31;
    #pragma unroll
    for (int i = 0; i < 4; ++i)
        tile[r + i * 8][c] = src[(size_t)(rb0 + r + i * 8) * C + cb0 + c];
    __syncthreads();
    #pragma unroll
    for (int i = 0; i < 4; ++i)
        dst[(size_t)(cb0 + r + i * 8) * R + rb0 + c] = f2bf(tile[c][r + i * 8]);
}

// ---------------------------------------------------------------------------
// k1_gemm: h1_raw = embb @ W1 + b1 (bf16). 128x128 tile, BK=64, 12 K-steps.
// Round-10: global_load_lds(16B) staging with linear [128][64] LDS and
// both-sides XOR swizzle (write: inverse-swizzled global src, lane l of a
// stripe s holds (row=s*8+(l>>3), ksl=(l&7)^((l>>3)&7)); read: slot^(row&7)).
__global__ __launch_bounds__(256) void k1_gemm(
    const ushort* __restrict__ embb, const ushort* __restrict__ W1t,
    const float* __restrict__ b1, ushort* __restrict__ h1raw)
{
    __shared__ ushort smem[2 * 128 * 64];   // Asm | Bsm = 32 KB; reused for C-stage
    ushort* Asm = smem;
    ushort* Bsm = smem + 128 * 64;

    const int t    = threadIdx.x;
    const int lane = t & 63;
    const int wid  = t >> 6;
    const int wm   = wid >> 1;
    const int wn   = wid & 1;
    const int l16  = lane & 15;
    const int sl0  = lane >> 4;         // 0..3: 16B slot base within K-half
    const int g4   = (lane >> 4) * 4;

    const int srow = lane >> 3;         // staging: row within 8-row stripe
    const int ssl  = (lane & 7) ^ srow; // staging: swizzled k-slot

    const int rb = blockIdx.y * 128;    // M tile
    const int cb = blockIdx.x * 128;    // N tile (over NH1=512)

    f32x4 acc[4][4] = {};

    for (int ks = 0; ks < 12; ++ks) {
        const int k0 = ks * 64;
        __syncthreads();   // prior MFMA reads done before LDS overwrite
        #pragma unroll
        for (int i = 0; i < 4; ++i) {
            const int stripe = wid * 4 + i;         // 0..15
            const int row    = stripe * 8 + srow;
            gload_lds16(&embb[(size_t)(rb + row) * DD + k0 + ssl * 8],
                        &Asm[stripe * 512]);
            gload_lds16(&W1t [(size_t)(cb + row) * DD + k0 + ssl * 8],
                        &Bsm[stripe * 512]);
        }
        __syncthreads();   // vmcnt(0) drain + barrier -> staged visible

        #pragma unroll
        for (int kk = 0; kk < 2; ++kk) {
            const int slot = kk * 4 + sl0;          // 0..7
            bf16x8 af[4], bfr[4];
            #pragma unroll
            for (int m = 0; m < 4; ++m) {
                const int R = wm * 64 + m * 16 + l16;
                af[m] = *(const bf16x8*)&Asm[R * 64 + (slot ^ (R & 7)) * 8];
            }
            #pragma unroll
            for (int n = 0; n < 4; ++n) {
                const int R = wn * 64 + n * 16 + l16;
                bfr[n] = *(const bf16x8*)&Bsm[R * 64 + (slot ^ (R & 7)) * 8];
            }
            #pragma unroll
            for (int m = 0; m < 4; ++m)
                #pragma unroll
                for (int n = 0; n < 4; ++n)
                    acc[m][n] = __builtin_amdgcn_mfma_f32_16x16x32_bf16(
                        af[m], bfr[n], acc[m][n], 0, 0, 0);
        }
    }

    float bv[4];
    #pragma unroll
    for (int n = 0; n < 4; ++n)
        bv[n] = b1[cb + wn * 64 + n * 16 + l16];

    __syncthreads();
    #pragma unroll
    for (int m = 0; m < 4; ++m)
        #pragma unroll
        for (int n = 0; n < 4; ++n)
            #pragma unroll
            for (int j = 0; j < 4; ++j)
                smem[(wm * 64 + m * 16 + g4 + j) * 128 + wn * 64 + n * 16 + l16] =
                    f2bf(acc[m][n][j] + bv[n]);
    __syncthreads();
    #pragma unroll
    for (int i = 0; i < 8; ++i) {
        int ch  = t + i * 256;              // 2048 chunks of 16 B
        int row = ch >> 4;
        int q   = ch & 15;
        *(int4*)&h1raw[(size_t)(rb + row) * NH1 + cb + q * 8] =
            *(const int4*)&smem[row * 128 + q * 8];
    }
}

// ---------------------------------------------------------------------------
// k1_ln: in-place LN+relu over h1 rows (512 bf16). One wave per row.
__global__ __launch_bounds__(256) void k1_ln(
    ushort* h1, const float* __restrict__ g1, const float* __restrict__ be1)
{
    const int lane = threadIdx.x & 63;
    const int w    = threadIdx.x >> 6;
    const size_t row = (size_t)blockIdx.x * 4 + w;

    ushort* p = h1 + row * NH1 + lane * 8;
    ushort u[8];
    *(int4*)u = *(const int4*)p;
    float x[8];
    float s = 0.f, q = 0.f;
    #pragma unroll
    for (int j = 0; j < 8; ++j) {
        x[j] = bf2f(u[j]);
        s += x[j];
        q += x[j] * x[j];
    }
    #pragma unroll
    for (int off = 32; off; off >>= 1) {
        s += __shfl_xor(s, off);
        q += __shfl_xor(q, off);
    }
    const float mu  = s * (1.f / NH1);
    const float var = q * (1.f / NH1) - mu * mu;
    const float rs  = rsqrtf(var + 1e-5f);

    float gv[8], ev[8];
    *(float4*)&gv[0] = *(const float4*)&g1[lane * 8];
    *(float4*)&gv[4] = *(const float4*)&g1[lane * 8 + 4];
    *(float4*)&ev[0] = *(const float4*)&be1[lane * 8];
    *(float4*)&ev[4] = *(const float4*)&be1[lane * 8 + 4];
    #pragma unroll
    for (int j = 0; j < 8; ++j)
        u[j] = f2bf(fmaxf(fmaf((x[j] - mu) * rs, gv[j], ev[j]), 0.f));
    *(int4*)p = *(int4*)u;
}

// ---------------------------------------------------------------------------
// k2 (MFMA, fused LN+relu): h2 = relu(LN(h1 @ W2 + b2)) stored bf16
__global__ __launch_bounds__(512) void k2_mfma(
    const ushort* __restrict__ h1, const ushort* __restrict__ W2t,
    const float* __restrict__ b2, const float* __restrict__ g2,
    const float* __restrict__ be2, ushort* __restrict__ h2)
{
    __shared__ ushort Asm[64 * 72];     //  9.2 KB
    __shared__ ushort Bsm[256 * 72];    // 36.9 KB
    __shared__ float red[8][64][2];
    __shared__ float stats[64][2];

    const int t    = threadIdx.x;
    const int lane = t & 63;
    const int wid  = t >> 6;
    const int wm   = wid >> 2;          // 0..1
    const int wn   = wid & 3;           // 0..3
    const int l16  = lane & 15;
    const int g8   = (lane >> 4) * 8;
    const int g4   = (lane >> 4) * 4;
    const int rb   = blockIdx.x * 64;

    const int arow = t >> 3, asl = t & 7;   // A: 512 chunks, 1/thread

    f32x4 acc[2][4] = {};

    for (int ks = 0; ks < 8; ++ks) {
        const int k0 = ks * 64;
        int4 ra = *(const int4*)&h1[(size_t)(rb + arow) * NH1 + k0 + asl * 8];
        int4 rbv[4];
        #pragma unroll
        for (int i = 0; i < 4; ++i) {
            int ch = t + i * 512;           // B: 2048 chunks, 4/thread
            int row = ch >> 3, sl = ch & 7;
            rbv[i] = *(const int4*)&W2t[(size_t)row * NH1 + k0 + sl * 8];
        }
        __syncthreads();
        *(int4*)&Asm[arow * 72 + asl * 8] = ra;
        #pragma unroll
        for (int i = 0; i < 4; ++i) {
            int ch = t + i * 512;
            int row = ch >> 3, sl = ch & 7;
            *(int4*)&Bsm[row * 72 + sl * 8] = rbv[i];
        }
        __syncthreads();

        #pragma unroll
        for (int kk = 0; kk < 2; ++kk) {
            bf16x8 af[2], bfr[4];
            #pragma unroll
            for (int m = 0; m < 2; ++m)
                af[m] = *(const bf16x8*)&Asm[(wm * 32 + m * 16 + l16) * 72 + kk * 32 + g8];
            #pragma unroll
            for (int n = 0; n < 4; ++n)
                bfr[n] = *(const bf16x8*)&Bsm[(wn * 64 + n * 16 + l16) * 72 + kk * 32 + g8];
            #pragma unroll
            for (int m = 0; m < 2; ++m)
                #pragma unroll
                for (int n = 0; n < 4; ++n)
                    acc[m][n] = __builtin_amdgcn_mfma_f32_16x16x32_bf16(
                        af[m], bfr[n], acc[m][n], 0, 0, 0);
        }
    }

    float bv[4];
    #pragma unroll
    for (int n = 0; n < 4; ++n) bv[n] = b2[wn * 64 + n * 16 + l16];
    #pragma unroll
    for (int m = 0; m < 2; ++m)
        #pragma unroll
        for (int n = 0; n < 4; ++n)
            #pragma unroll
            for (int j = 0; j < 4; ++j) acc[m][n][j] += bv[n];

    #pragma unroll
    for (int m = 0; m < 2; ++m)
        #pragma unroll
        for (int j = 0; j < 4; ++j) {
            float p = 0.f, q = 0.f;
            #pragma unroll
            for (int n = 0; n < 4; ++n) {
                float v = acc[m][n][j];
                p += v; q += v * v;
            }
            #pragma unroll
            for (int off = 8; off; off >>= 1) {
                p += __shfl_xor(p, off);
                q += __shfl_xor(q, off);
            }
            if (l16 == 0) {
                red[wid][wm * 32 + m * 16 + g4 + j][0] = p;
                red[wid][wm * 32 + m * 16 + g4 + j][1] = q;
            }
        }
    __syncthreads();
    if (t < 64) {
        const int w0 = (t >> 5) * 4;
        float S = 0.f, S2 = 0.f;
        #pragma unroll
        for (int w = 0; w < 4; ++w) { S += red[w0 + w][t][0]; S2 += red[w0 + w][t][1]; }
        float mu  = S  * (1.f / NH2);
        float var = S2 * (1.f / NH2) - mu * mu;
        stats[t][0] = mu;
        stats[t][1] = rsqrtf(var + 1e-5f);
    }
    __syncthreads();

    float gv[4], ev[4];
    #pragma unroll
    for (int n = 0; n < 4; ++n) {
        int col = wn * 64 + n * 16 + l16;
        gv[n] = g2[col]; ev[n] = be2[col];
    }
    ushort* dst = h2 + (size_t)rb * NH2;
    #pragma unroll
    for (int m = 0; m < 2; ++m)
        #pragma unroll
        for (int j = 0; j < 4; ++j) {
            int row = wm * 32 + m * 16 + g4 + j;
            float mu = stats[row][0], rs = stats[row][1];
            #pragma unroll
            for (int n = 0; n < 4; ++n) {
                float val = fmaxf(fmaf((acc[m][n][j] - mu) * rs, gv[n], ev[n]), 0.f);
                dst[(size_t)row * NH2 + wn * 64 + n * 16 + l16] = f2bf(val);
            }
        }
}

// ---------------------------------------------------------------------------
// k3a: W_flat(bf16) = h2 @ Wd + bd, packed into second half of out rows.
// Round-10: same global_load_lds + XOR-swizzle staging as k1_gemm.
__global__ __launch_bounds__(256) void k_gemm_wd_mfma(
    const ushort* __restrict__ h2, const ushort* __restrict__ Wdt,
    const float* __restrict__ bd, ushort* __restrict__ outw)
{
    __shared__ ushort smem[2 * 128 * 64];   // Asm | Bsm = 32 KB; reused for C-stage
    ushort* Asm = smem;
    ushort* Bsm = smem + 128 * 64;

    const int t    = threadIdx.x;
    const int lane = t & 63;
    const int wid  = t >> 6;
    const int wm   = wid >> 1;
    const int wn   = wid & 1;
    const int l16  = lane & 15;
    const int sl0  = lane >> 4;
    const int g4   = (lane >> 4) * 4;

    const int srow = lane >> 3;
    const int ssl  = (lane & 7) ^ srow;

    const int rb = blockIdx.y * 128;
    const int cb = blockIdx.x * 128;

    f32x4 acc[4][4] = {};

    for (int ks = 0; ks < 4; ++ks) {
        const int k0 = ks * 64;
        __syncthreads();
        #pragma unroll
        for (int i = 0; i < 4; ++i) {
            const int stripe = wid * 4 + i;
            const int row    = stripe * 8 + srow;
            gload_lds16(&h2 [(size_t)(rb + row) * NH2 + k0 + ssl * 8],
                        &Asm[stripe * 512]);
            gload_lds16(&Wdt[(size_t)(cb + row) * NH2 + k0 + ssl * 8],
                        &Bsm[stripe * 512]);
        }
        __syncthreads();

        #pragma unroll
        for (int kk = 0; kk < 2; ++kk) {
            const int slot = kk * 4 + sl0;
            bf16x8 af[4], bfr[4];
            #pragma unroll
            for (int m = 0; m < 4; ++m) {
                const int R = wm * 64 + m * 16 + l16;
                af[m] = *(const bf16x8*)&Asm[R * 64 + (slot ^ (R & 7)) * 8];
            }
            #pragma unroll
            for (int n = 0; n < 4; ++n) {
                const int R = wn * 64 + n * 16 + l16;
                bfr[n] = *(const bf16x8*)&Bsm[R * 64 + (slot ^ (R & 7)) * 8];
            }
            #pragma unroll
            for (int m = 0; m < 4; ++m)
                #pragma unroll
                for (int n = 0; n < 4; ++n)
                    acc[m][n] = __builtin_amdgcn_mfma_f32_16x16x32_bf16(
                        af[m], bfr[n], acc[m][n], 0, 0, 0);
        }
    }

    float bv[4];
    #pragma unroll
    for (int n = 0; n < 4; ++n)
        bv[n] = bd[cb + wn * 64 + n * 16 + l16];

    __syncthreads();
    #pragma unroll
    for (int m = 0; m < 4; ++m)
        #pragma unroll
        for (int n = 0; n < 4; ++n)
            #pragma unroll
            for (int j = 0; j < 4; ++j)
                smem[(wm * 64 + m * 16 + g4 + j) * 128 + wn * 64 + n * 16 + l16] =
                    f2bf(acc[m][n][j] + bv[n]);
    __syncthreads();
    #pragma unroll
    for (int i = 0; i < 8; ++i) {
        int ch  = t + i * 256;
        int row = ch >> 4;
        int q   = ch & 15;
        *(int4*)&outw[(size_t)(rb + row) * 6144 + 3072 + cb + q * 8] =
            *(const int4*)&smem[row * 128 + q * 8];
    }
}

// ---------------------------------------------------------------------------
// k3b (MFMA, fused softmax): attn = softmax(h2 @ Wa + ba)
__global__ __launch_bounds__(512) void k_attn_mfma(
    const ushort* __restrict__ h2, const ushort* __restrict__ Wat,
    const float* __restrict__ ba, float* __restrict__ attn)
{
    __shared__ ushort Asm[64 * 72];      //   9.2 KB
    __shared__ ushort Bsm[768 * 72];     // 110.6 KB (reused as f32 stage [32][776])
    __shared__ float red[8][64];
    __shared__ float stats[64];

    const int t    = threadIdx.x;
    const int lane = t & 63;
    const int wid  = t >> 6;
    const int wm   = wid >> 2;          // 0..1
    const int wn   = wid & 3;           // 0..3
    const int l16  = lane & 15;
    const int g8   = (lane >> 4) * 8;
    const int g4   = (lane >> 4) * 4;
    const int rb   = blockIdx.x * 64;

    const int arow = t >> 3, asl = t & 7;

    f32x4 acc[2][12] = {};

    for (int ks = 0; ks < 4; ++ks) {
        const int k0 = ks * 64;
        int4 ra = *(const int4*)&h2[(size_t)(rb + arow) * NH2 + k0 + asl * 8];
        int4 rbv[12];
        #pragma unroll
        for (int i = 0; i < 12; ++i) {
            int ch = t + i * 512;           // B: 6144 chunks, 12/thread
            int row = ch >> 3, sl = ch & 7;
            rbv[i] = *(const int4*)&Wat[(size_t)row * NH2 + k0 + sl * 8];
        }
        __syncthreads();
        *(int4*)&Asm[arow * 72 + asl * 8] = ra;
        #pragma unroll
        for (int i = 0; i < 12; ++i) {
            int ch = t + i * 512;
            int row = ch >> 3, sl = ch & 7;
            *(int4*)&Bsm[row * 72 + sl * 8] = rbv[i];
        }
        __syncthreads();

        #pragma unroll
        for (int kk = 0; kk < 2; ++kk) {
            bf16x8 af[2], bfr[12];
            #pragma unroll
            for (int m = 0; m < 2; ++m)
                af[m] = *(const bf16x8*)&Asm[(wm * 32 + m * 16 + l16) * 72 + kk * 32 + g8];
            #pragma unroll
            for (int n = 0; n < 12; ++n)
                bfr[n] = *(const bf16x8*)&Bsm[(wn * 192 + n * 16 + l16) * 72 + kk * 32 + g8];
            #pragma unroll
            for (int m = 0; m < 2; ++m)
                #pragma unroll
                for (int n = 0; n < 12; ++n)
                    acc[m][n] = __builtin_amdgcn_mfma_f32_16x16x32_bf16(
                        af[m], bfr[n], acc[m][n], 0, 0, 0);
        }
    }

    // bias
    float bb[12];
    #pragma unroll
    for (int n = 0; n < 12; ++n) bb[n] = ba[wn * 192 + n * 16 + l16];
    #pragma unroll
    for (int m = 0; m < 2; ++m)
        #pragma unroll
        for (int n = 0; n < 12; ++n)
            #pragma unroll
            for (int j = 0; j < 4; ++j) acc[m][n][j] += bb[n];

    // row max
    #pragma unroll
    for (int m = 0; m < 2; ++m)
        #pragma unroll
        for (int j = 0; j < 4; ++j) {
            float p = acc[m][0][j];
            #pragma unroll
            for (int n = 1; n < 12; ++n) p = fmaxf(p, acc[m][n][j]);
            #pragma unroll
            for (int off = 8; off; off >>= 1) p = fmaxf(p, __shfl_xor(p, off));
            if (l16 == 0) red[wid][wm * 32 + m * 16 + g4 + j] = p;
        }
    __syncthreads();
    if (t < 64) {
        const int w0 = (t >> 5) * 4;
        stats[t] = fmaxf(fmaxf(red[w0][t], red[w0 + 1][t]),
                         fmaxf(red[w0 + 2][t], red[w0 + 3][t]));
    }
    __syncthreads();
    // exp + row sum
    #pragma unroll
    for (int m = 0; m < 2; ++m)
        #pragma unroll
        for (int j = 0; j < 4; ++j) {
            float M = stats[wm * 32 + m * 16 + g4 + j];
            float s = 0.f;
            #pragma unroll
            for (int n = 0; n < 12; ++n) {
                acc[m][n][j] = __expf(acc[m][n][j] - M);
                s += acc[m][n][j];
            }
            #pragma unroll
            for (int off = 8; off; off >>= 1) s += __shfl_xor(s, off);
            if (l16 == 0) red[wid][wm * 32 + m * 16 + g4 + j] = s;
        }
    __syncthreads();
    if (t < 64) {
        const int w0 = (t >> 5) * 4;
        stats[t] = 1.f / (red[w0][t] + red[w0 + 1][t] + red[w0 + 2][t] + red[w0 + 3][t]);
    }
    __syncthreads();

    // staged fp32 output, two 32-row passes (stride 776 floats: conflict-free)
    float* stage = (float*)Bsm;
    #pragma unroll
    for (int h = 0; h < 2; ++h) {
        if (wm == h) {
            #pragma unroll
            for (int m = 0; m < 2; ++m)
                #pragma unroll
                for (int j = 0; j < 4; ++j) {
                    const int r = m * 16 + g4 + j;
                    const float inv = stats[h * 32 + r];
                    #pragma unroll
                    for (int n = 0; n < 12; ++n)
                        stage[r * 776 + wn * 192 + n * 16 + l16] = acc[m][n][j] * inv;
                }
        }
        __syncthreads();
        #pragma unroll
        for (int i = 0; i < 12; ++i) {
            int ch  = t + i * 512;          // 6144 chunks of 16 B
            int row = ch / 192;
            int q   = ch - row * 192;
            *(float4*)&attn[(size_t)(rb + h * 32 + row) * DD + q * 4] =
                *(const float4*)&stage[row * 776 + q * 4];
        }
        __syncthreads();
    }
}

// ---------------------------------------------------------------------------
// k4: per row: W = Wflat_bf16 * attn; modified Gram-Schmidt; normalize.
__global__ __launch_bounds__(256) void k_gs(float* __restrict__ out)
{
    const int wid  = threadIdx.x >> 6;
    const int lane = threadIdx.x & 63;
    const size_t row = (size_t)blockIdx.x * 4 + wid;

    float* Wf = out + row * (KK * DD);
    const ushort* wsrc = (const ushort*)out + row * 6144 + 3072;
    const float* at = out + (size_t)BSZ * (KK * DD) + row * DD;

    float a[12];
    #pragma unroll
    for (int k = 0; k < 3; ++k) {
        float4 av = *(const float4*)&at[lane * 4 + 256 * k];
        a[k * 4 + 0] = av.x; a[k * 4 + 1] = av.y;
        a[k * 4 + 2] = av.z; a[k * 4 + 3] = av.w;
    }
    float w[4][12];
    #pragma unroll
    for (int i = 0; i < 4; ++i) {
        #pragma unroll
        for (int k = 0; k < 3; ++k) {
            ushort4 uv = *(const ushort4*)&wsrc[i * DD + lane * 4 + 256 * k];
            w[i][k * 4 + 0] = bf2f(uv.x) * a[k * 4 + 0];
            w[i][k * 4 + 1] = bf2f(uv.y) * a[k * 4 + 1];
            w[i][k * 4 + 2] = bf2f(uv.z) * a[k * 4 + 2];
            w[i][k * 4 + 3] = bf2f(uv.w) * a[k * 4 + 3];
        }
    }
    #pragma unroll
    for (int i = 0; i < 4; ++i) {
        #pragma unroll
        for (int p = 0; p < i; ++p) {
            float s = 0.f;
            #pragma unroll
            for (int j = 0; j < 12; ++j) s = fmaf(w[i][j], w[p][j], s);
            #pragma unroll
            for (int off = 32; off; off >>= 1) s += __shfl_xor(s, off);
            #pragma unroll
            for (int j = 0; j < 12; ++j) w[i][j] = fmaf(-s, w[p][j], w[i][j]);
        }
        float n2 = 0.f;
        #pragma unroll
        for (int j = 0; j < 12; ++j) n2 = fmaf(w[i][j], w[i][j], n2);
        #pragma unroll
        for (int off = 32; off; off >>= 1) n2 += __shfl_xor(n2, off);
        float inv = 1.f / fmaxf(sqrtf(n2), 1e-12f);
        #pragma unroll
        for (int j = 0; j < 12; ++j) w[i][j] *= inv;
    }
    #pragma unroll
    for (int i = 0; i < 4; ++i) {
        #pragma unroll
        for (int k = 0; k < 3; ++k) {
            float4 wv;
            wv.x = w[i][k * 4 + 0]; wv.y = w[i][k * 4 + 1];
            wv.z = w[i][k * 4 + 2]; wv.w = w[i][k * 4 + 3];
            *(float4*)&Wf[i * DD + lane * 4 + 256 * k] = wv;
        }
    }
}

// ---------------------------------------------------------------------------
extern "C" void kernel_launch(void* const* d_in, const int* in_sizes, int n_in,
                              void* d_out, int out_size, void* d_ws, size_t ws_size,
                              hipStream_t stream)
{
    const float* emb = (const float*)d_in[0];
    const float* W1  = (const float*)d_in[1];
    const float* b1  = (const float*)d_in[2];
    const float* g1  = (const float*)d_in[3];
    const float* be1 = (const float*)d_in[4];
    const float* W2  = (const float*)d_in[5];
    const float* b2  = (const float*)d_in[6];
    const float* g2  = (const float*)d_in[7];
    const float* be2 = (const float*)d_in[8];
    const float* Wd  = (const float*)d_in[9];
    const float* bd  = (const float*)d_in[10];
    const float* Wa  = (const float*)d_in[11];
    const float* ba  = (const float*)d_in[12];

    float* out = (float*)d_out;
    ushort* h1   = (ushort*)d_ws;                // B*512 bf16 = 16.8 MB
    ushort* h2   = h1 + (size_t)BSZ * NH1;       // B*256 bf16 =  8.4 MB
    ushort* Wdt  = h2 + (size_t)BSZ * NH2;       // 3072*256 bf16 = 1.5 MB
    ushort* W1t  = Wdt + (size_t)ND * NH2;       // 512*768 bf16 = 0.77 MB
    ushort* W2t  = W1t + (size_t)NH1 * DD;       // 256*512 bf16 = 0.25 MB
    ushort* Wat  = W2t + (size_t)NH2 * NH1;      // 768*256 bf16 = 0.39 MB
    ushort* embb = Wat + (size_t)DD * NH2;       // B*768 bf16 = 25.2 MB
    float* attn = out + (size_t)BSZ * KK * DD;   // attn region of out, B*D

    hipLaunchKernelGGL(k_cvt_emb, dim3(2048), dim3(256), 0, stream,
                       emb, embb, BSZ * DD / 8);
    hipLaunchKernelGGL(k_t_cvt, dim3(NH1 / 32, DD / 32), dim3(256), 0, stream,
                       W1, W1t, DD, NH1);        // W1 (768x512) -> W1t (512x768)
    hipLaunchKernelGGL(k_t_cvt, dim3(NH2 / 32, NH1 / 32), dim3(256), 0, stream,
                       W2, W2t, NH1, NH2);       // W2 (512x256) -> W2t (256x512)
    hipLaunchKernelGGL(k_t_cvt, dim3(ND / 32, NH2 / 32), dim3(256), 0, stream,
                       Wd, Wdt, NH2, ND);        // Wd (256x3072) -> Wdt (3072x256)
    hipLaunchKernelGGL(k_t_cvt, dim3(DD / 32, NH2 / 32), dim3(256), 0, stream,
                       Wa, Wat, NH2, DD);        // Wa (256x768) -> Wat (768x256)
    hipLaunchKernelGGL(k1_gemm, dim3(NH1 / 128, BSZ / 128), dim3(256), 0, stream,
                       embb, W1t, b1, h1);
    hipLaunchKernelGGL(k1_ln, dim3(BSZ / 4), dim3(256), 0, stream,
                       h1, g1, be1);
    hipLaunchKernelGGL(k2_mfma, dim3(BSZ / 64), dim3(512), 0, stream,
                       h1, W2t, b2, g2, be2, h2);
    hipLaunchKernelGGL(k_gemm_wd_mfma, dim3(ND / 128, BSZ / 128), dim3(256), 0, stream,
                       h2, Wdt, bd, (ushort*)out);
    hipLaunchKernelGGL(k_attn_mfma, dim3(BSZ / 64), dim3(512), 0, stream,
                       h2, Wat, ba, attn);
    hipLaunchKernelGGL(k_gs, dim3(BSZ / 4), dim3(256), 0, stream, out);
}

// Round 11
// 188.872 us; speedup vs baseline: 1.9203x; 1.2193x over previous
//
#include <hip/hip_runtime.h>
#include <hip/hip_bf16.h>

#define BSZ 16384
#define DD  768
#define KK  4
#define NH1 512
#define NH2 256
#define ND  (KK * DD)   // 3072

typedef __bf16 bf16x8 __attribute__((ext_vector_type(8)));
typedef float  f32x4  __attribute__((ext_vector_type(4)));

static __device__ __forceinline__ float bf2f(ushort u) {
    union { unsigned int i; float f; } v; v.i = (unsigned int)u << 16; return v.f;
}
static __device__ __forceinline__ ushort f2bf(float f) {
    return __bfloat16_as_ushort(__float2bfloat16(f));
}
// async global->LDS, 16B per lane; LDS dest = uniform base + lane*16
static __device__ __forceinline__ void gload_lds16(const void* g, void* l) {
    __builtin_amdgcn_global_load_lds(
        (const __attribute__((address_space(1))) void*)g,
        (__attribute__((address_space(3))) void*)l, 16, 0, 0);
}

// ---------------------------------------------------------------------------
// k_cvt_emb: emb fp32 -> bf16, row-major copy-convert (8 elems/thread/iter)
__global__ __launch_bounds__(256) void k_cvt_emb(
    const float* __restrict__ src, ushort* __restrict__ dst, int n8)
{
    const int stride = gridDim.x * 256;
    for (int i = blockIdx.x * 256 + threadIdx.x; i < n8; i += stride) {
        float4 a = *(const float4*)&src[(size_t)i * 8];
        float4 b = *(const float4*)&src[(size_t)i * 8 + 4];
        ushort u[8];
        u[0] = f2bf(a.x); u[1] = f2bf(a.y); u[2] = f2bf(a.z); u[3] = f2bf(a.w);
        u[4] = f2bf(b.x); u[5] = f2bf(b.y); u[6] = f2bf(b.z); u[7] = f2bf(b.w);
        *(int4*)&dst[(size_t)i * 8] = *(int4*)u;
    }
}

// ---------------------------------------------------------------------------
// k_t_cvt: src (R x C f32) -> dst (C x R bf16)  [generic transpose+convert]
__global__ __launch_bounds__(256) void k_t_cvt(
    const float* __restrict__ src, ushort* __restrict__ dst, int R, int C)
{
    __shared__ float tile[32][33];
    const int rb0 = blockIdx.y * 32;  // src row
    const int cb0 = blockIdx.x * 32;  // src col
    const int t = threadIdx.x;
    const int r = t >> 5, c = t & 31;
    #pragma unroll
    for (int i = 0; i < 4; ++i)
        tile[r + i * 8][c] = src[(size_t)(rb0 + r + i * 8) * C + cb0 + c];
    __syncthreads();
    #pragma unroll
    for (int i = 0; i < 4; ++i)
        dst[(size_t)(cb0 + r + i * 8) * R + rb0 + c] = f2bf(tile[c][r + i * 8]);
}

// ---------------------------------------------------------------------------
// k1_gemm: h1_raw = embb @ W1 + b1 (bf16). 128x128 tile, BK=64, 12 K-steps.
// global_load_lds(16B) staging, linear [128][64] LDS, both-sides XOR swizzle.
__global__ __launch_bounds__(256) void k1_gemm(
    const ushort* __restrict__ embb, const ushort* __restrict__ W1t,
    const float* __restrict__ b1, ushort* __restrict__ h1raw)
{
    __shared__ ushort smem[2 * 128 * 64];   // Asm | Bsm = 32 KB; reused for C-stage
    ushort* Asm = smem;
    ushort* Bsm = smem + 128 * 64;

    const int t    = threadIdx.x;
    const int lane = t & 63;
    const int wid  = t >> 6;
    const int wm   = wid >> 1;
    const int wn   = wid & 1;
    const int l16  = lane & 15;
    const int sl0  = lane >> 4;         // 0..3: 16B slot base within K-half
    const int g4   = (lane >> 4) * 4;

    const int srow = lane >> 3;         // staging: row within 8-row stripe
    const int ssl  = (lane & 7) ^ srow; // staging: swizzled k-slot

    const int rb = blockIdx.y * 128;    // M tile
    const int cb = blockIdx.x * 128;    // N tile (over NH1=512)

    f32x4 acc[4][4] = {};

    for (int ks = 0; ks < 12; ++ks) {
        const int k0 = ks * 64;
        __syncthreads();   // prior MFMA reads done before LDS overwrite
        #pragma unroll
        for (int i = 0; i < 4; ++i) {
            const int stripe = wid * 4 + i;         // 0..15
            const int row    = stripe * 8 + srow;
            gload_lds16(&embb[(size_t)(rb + row) * DD + k0 + ssl * 8],
                        &Asm[stripe * 512]);
            gload_lds16(&W1t [(size_t)(cb + row) * DD + k0 + ssl * 8],
                        &Bsm[stripe * 512]);
        }
        __syncthreads();   // vmcnt(0) drain + barrier -> staged visible

        #pragma unroll
        for (int kk = 0; kk < 2; ++kk) {
            const int slot = kk * 4 + sl0;          // 0..7
            bf16x8 af[4], bfr[4];
            #pragma unroll
            for (int m = 0; m < 4; ++m) {
                const int R = wm * 64 + m * 16 + l16;
                af[m] = *(const bf16x8*)&Asm[R * 64 + (slot ^ (R & 7)) * 8];
            }
            #pragma unroll
            for (int n = 0; n < 4; ++n) {
                const int R = wn * 64 + n * 16 + l16;
                bfr[n] = *(const bf16x8*)&Bsm[R * 64 + (slot ^ (R & 7)) * 8];
            }
            #pragma unroll
            for (int m = 0; m < 4; ++m)
                #pragma unroll
                for (int n = 0; n < 4; ++n)
                    acc[m][n] = __builtin_amdgcn_mfma_f32_16x16x32_bf16(
                        af[m], bfr[n], acc[m][n], 0, 0, 0);
        }
    }

    float bv[4];
    #pragma unroll
    for (int n = 0; n < 4; ++n)
        bv[n] = b1[cb + wn * 64 + n * 16 + l16];

    __syncthreads();
    #pragma unroll
    for (int m = 0; m < 4; ++m)
        #pragma unroll
        for (int n = 0; n < 4; ++n)
            #pragma unroll
            for (int j = 0; j < 4; ++j)
                smem[(wm * 64 + m * 16 + g4 + j) * 128 + wn * 64 + n * 16 + l16] =
                    f2bf(acc[m][n][j] + bv[n]);
    __syncthreads();
    #pragma unroll
    for (int i = 0; i < 8; ++i) {
        int ch  = t + i * 256;              // 2048 chunks of 16 B
        int row = ch >> 4;
        int q   = ch & 15;
        *(int4*)&h1raw[(size_t)(rb + row) * NH1 + cb + q * 8] =
            *(const int4*)&smem[row * 128 + q * 8];
    }
}

// ---------------------------------------------------------------------------
// k1_ln: in-place LN+relu over h1 rows (512 bf16). One wave per row.
__global__ __launch_bounds__(256) void k1_ln(
    ushort* h1, const float* __restrict__ g1, const float* __restrict__ be1)
{
    const int lane = threadIdx.x & 63;
    const int w    = threadIdx.x >> 6;
    const size_t row = (size_t)blockIdx.x * 4 + w;

    ushort* p = h1 + row * NH1 + lane * 8;
    ushort u[8];
    *(int4*)u = *(const int4*)p;
    float x[8];
    float s = 0.f, q = 0.f;
    #pragma unroll
    for (int j = 0; j < 8; ++j) {
        x[j] = bf2f(u[j]);
        s += x[j];
        q += x[j] * x[j];
    }
    #pragma unroll
    for (int off = 32; off; off >>= 1) {
        s += __shfl_xor(s, off);
        q += __shfl_xor(q, off);
    }
    const float mu  = s * (1.f / NH1);
    const float var = q * (1.f / NH1) - mu * mu;
    const float rs  = rsqrtf(var + 1e-5f);

    float gv[8], ev[8];
    *(float4*)&gv[0] = *(const float4*)&g1[lane * 8];
    *(float4*)&gv[4] = *(const float4*)&g1[lane * 8 + 4];
    *(float4*)&ev[0] = *(const float4*)&be1[lane * 8];
    *(float4*)&ev[4] = *(const float4*)&be1[lane * 8 + 4];
    #pragma unroll
    for (int j = 0; j < 8; ++j)
        u[j] = f2bf(fmaxf(fmaf((x[j] - mu) * rs, gv[j], ev[j]), 0.f));
    *(int4*)p = *(int4*)u;
}

// ---------------------------------------------------------------------------
// k2 (MFMA, fused LN+relu): h2 = relu(LN(h1 @ W2 + b2)) stored bf16.
// Round-11: staging -> global_load_lds, linear [64][64]/[256][64] LDS + swizzle.
__global__ __launch_bounds__(512) void k2_mfma(
    const ushort* __restrict__ h1, const ushort* __restrict__ W2t,
    const float* __restrict__ b2, const float* __restrict__ g2,
    const float* __restrict__ be2, ushort* __restrict__ h2)
{
    __shared__ ushort Asm[64 * 64];     //  8 KB
    __shared__ ushort Bsm[256 * 64];    // 32 KB
    __shared__ float red[8][64][2];
    __shared__ float stats[64][2];

    const int t    = threadIdx.x;
    const int lane = t & 63;
    const int wid  = t >> 6;            // 0..7
    const int wm   = wid >> 2;          // 0..1
    const int wn   = wid & 3;           // 0..3
    const int l16  = lane & 15;
    const int sl0  = lane >> 4;
    const int g4   = (lane >> 4) * 4;
    const int rb   = blockIdx.x * 64;

    const int srow = lane >> 3;
    const int ssl  = (lane & 7) ^ srow;

    f32x4 acc[2][4] = {};

    for (int ks = 0; ks < 8; ++ks) {
        const int k0 = ks * 64;
        __syncthreads();
        // A: 8 stripes, wave w -> stripe w
        {
            const int row = wid * 8 + srow;
            gload_lds16(&h1[(size_t)(rb + row) * NH1 + k0 + ssl * 8],
                        &Asm[wid * 512]);
        }
        // B: 32 stripes, wave w -> stripes 4w..4w+3
        #pragma unroll
        for (int i = 0; i < 4; ++i) {
            const int stripe = wid * 4 + i;
            const int row    = stripe * 8 + srow;
            gload_lds16(&W2t[(size_t)row * NH1 + k0 + ssl * 8],
                        &Bsm[stripe * 512]);
        }
        __syncthreads();

        #pragma unroll
        for (int kk = 0; kk < 2; ++kk) {
            const int slot = kk * 4 + sl0;
            bf16x8 af[2], bfr[4];
            #pragma unroll
            for (int m = 0; m < 2; ++m) {
                const int R = wm * 32 + m * 16 + l16;
                af[m] = *(const bf16x8*)&Asm[R * 64 + (slot ^ (R & 7)) * 8];
            }
            #pragma unroll
            for (int n = 0; n < 4; ++n) {
                const int R = wn * 64 + n * 16 + l16;
                bfr[n] = *(const bf16x8*)&Bsm[R * 64 + (slot ^ (R & 7)) * 8];
            }
            #pragma unroll
            for (int m = 0; m < 2; ++m)
                #pragma unroll
                for (int n = 0; n < 4; ++n)
                    acc[m][n] = __builtin_amdgcn_mfma_f32_16x16x32_bf16(
                        af[m], bfr[n], acc[m][n], 0, 0, 0);
        }
    }

    float bv[4];
    #pragma unroll
    for (int n = 0; n < 4; ++n) bv[n] = b2[wn * 64 + n * 16 + l16];
    #pragma unroll
    for (int m = 0; m < 2; ++m)
        #pragma unroll
        for (int n = 0; n < 4; ++n)
            #pragma unroll
            for (int j = 0; j < 4; ++j) acc[m][n][j] += bv[n];

    #pragma unroll
    for (int m = 0; m < 2; ++m)
        #pragma unroll
        for (int j = 0; j < 4; ++j) {
            float p = 0.f, q = 0.f;
            #pragma unroll
            for (int n = 0; n < 4; ++n) {
                float v = acc[m][n][j];
                p += v; q += v * v;
            }
            #pragma unroll
            for (int off = 8; off; off >>= 1) {
                p += __shfl_xor(p, off);
                q += __shfl_xor(q, off);
            }
            if (l16 == 0) {
                red[wid][wm * 32 + m * 16 + g4 + j][0] = p;
                red[wid][wm * 32 + m * 16 + g4 + j][1] = q;
            }
        }
    __syncthreads();
    if (t < 64) {
        const int w0 = (t >> 5) * 4;
        float S = 0.f, S2 = 0.f;
        #pragma unroll
        for (int w = 0; w < 4; ++w) { S += red[w0 + w][t][0]; S2 += red[w0 + w][t][1]; }
        float mu  = S  * (1.f / NH2);
        float var = S2 * (1.f / NH2) - mu * mu;
        stats[t][0] = mu;
        stats[t][1] = rsqrtf(var + 1e-5f);
    }
    __syncthreads();

    float gv[4], ev[4];
    #pragma unroll
    for (int n = 0; n < 4; ++n) {
        int col = wn * 64 + n * 16 + l16;
        gv[n] = g2[col]; ev[n] = be2[col];
    }
    ushort* dst = h2 + (size_t)rb * NH2;
    #pragma unroll
    for (int m = 0; m < 2; ++m)
        #pragma unroll
        for (int j = 0; j < 4; ++j) {
            int row = wm * 32 + m * 16 + g4 + j;
            float mu = stats[row][0], rs = stats[row][1];
            #pragma unroll
            for (int n = 0; n < 4; ++n) {
                float val = fmaxf(fmaf((acc[m][n][j] - mu) * rs, gv[n], ev[n]), 0.f);
                dst[(size_t)row * NH2 + wn * 64 + n * 16 + l16] = f2bf(val);
            }
        }
}

// ---------------------------------------------------------------------------
// k3a: W_flat(bf16) = h2 @ Wd + bd, packed into second half of out rows.
// global_load_lds + XOR-swizzle staging (proven round-10).
__global__ __launch_bounds__(256) void k_gemm_wd_mfma(
    const ushort* __restrict__ h2, const ushort* __restrict__ Wdt,
    const float* __restrict__ bd, ushort* __restrict__ outw)
{
    __shared__ ushort smem[2 * 128 * 64];   // Asm | Bsm = 32 KB; reused for C-stage
    ushort* Asm = smem;
    ushort* Bsm = smem + 128 * 64;

    const int t    = threadIdx.x;
    const int lane = t & 63;
    const int wid  = t >> 6;
    const int wm   = wid >> 1;
    const int wn   = wid & 1;
    const int l16  = lane & 15;
    const int sl0  = lane >> 4;
    const int g4   = (lane >> 4) * 4;

    const int srow = lane >> 3;
    const int ssl  = (lane & 7) ^ srow;

    const int rb = blockIdx.y * 128;
    const int cb = blockIdx.x * 128;

    f32x4 acc[4][4] = {};

    for (int ks = 0; ks < 4; ++ks) {
        const int k0 = ks * 64;
        __syncthreads();
        #pragma unroll
        for (int i = 0; i < 4; ++i) {
            const int stripe = wid * 4 + i;
            const int row    = stripe * 8 + srow;
            gload_lds16(&h2 [(size_t)(rb + row) * NH2 + k0 + ssl * 8],
                        &Asm[stripe * 512]);
            gload_lds16(&Wdt[(size_t)(cb + row) * NH2 + k0 + ssl * 8],
                        &Bsm[stripe * 512]);
        }
        __syncthreads();

        #pragma unroll
        for (int kk = 0; kk < 2; ++kk) {
            const int slot = kk * 4 + sl0;
            bf16x8 af[4], bfr[4];
            #pragma unroll
            for (int m = 0; m < 4; ++m) {
                const int R = wm * 64 + m * 16 + l16;
                af[m] = *(const bf16x8*)&Asm[R * 64 + (slot ^ (R & 7)) * 8];
            }
            #pragma unroll
            for (int n = 0; n < 4; ++n) {
                const int R = wn * 64 + n * 16 + l16;
                bfr[n] = *(const bf16x8*)&Bsm[R * 64 + (slot ^ (R & 7)) * 8];
            }
            #pragma unroll
            for (int m = 0; m < 4; ++m)
                #pragma unroll
                for (int n = 0; n < 4; ++n)
                    acc[m][n] = __builtin_amdgcn_mfma_f32_16x16x32_bf16(
                        af[m], bfr[n], acc[m][n], 0, 0, 0);
        }
    }

    float bv[4];
    #pragma unroll
    for (int n = 0; n < 4; ++n)
        bv[n] = bd[cb + wn * 64 + n * 16 + l16];

    __syncthreads();
    #pragma unroll
    for (int m = 0; m < 4; ++m)
        #pragma unroll
        for (int n = 0; n < 4; ++n)
            #pragma unroll
            for (int j = 0; j < 4; ++j)
                smem[(wm * 64 + m * 16 + g4 + j) * 128 + wn * 64 + n * 16 + l16] =
                    f2bf(acc[m][n][j] + bv[n]);
    __syncthreads();
    #pragma unroll
    for (int i = 0; i < 8; ++i) {
        int ch  = t + i * 256;
        int row = ch >> 4;
        int q   = ch & 15;
        *(int4*)&outw[(size_t)(rb + row) * 6144 + 3072 + cb + q * 8] =
            *(const int4*)&smem[row * 128 + q * 8];
    }
}

// ---------------------------------------------------------------------------
// k3b (MFMA, fused softmax): attn = softmax(h2 @ Wa + ba)
// Round-11: staging -> global_load_lds, linear [64][64]/[768][64] LDS + swizzle.
// fp32 output stage reuses Bsm at stride 768 (96 KB exactly).
__global__ __launch_bounds__(512) void k_attn_mfma(
    const ushort* __restrict__ h2, const ushort* __restrict__ Wat,
    const float* __restrict__ ba, float* __restrict__ attn)
{
    __shared__ ushort Asm[64 * 64];      //  8 KB
    __shared__ ushort Bsm[768 * 64];     // 96 KB (reused as f32 stage [32][768])
    __shared__ float red[8][64];
    __shared__ float stats[64];

    const int t    = threadIdx.x;
    const int lane = t & 63;
    const int wid  = t >> 6;            // 0..7
    const int wm   = wid >> 2;          // 0..1
    const int wn   = wid & 3;           // 0..3
    const int l16  = lane & 15;
    const int sl0  = lane >> 4;
    const int g4   = (lane >> 4) * 4;
    const int rb   = blockIdx.x * 64;

    const int srow = lane >> 3;
    const int ssl  = (lane & 7) ^ srow;

    f32x4 acc[2][12] = {};

    for (int ks = 0; ks < 4; ++ks) {
        const int k0 = ks * 64;
        __syncthreads();
        // A: 8 stripes, wave w -> stripe w
        {
            const int row = wid * 8 + srow;
            gload_lds16(&h2[(size_t)(rb + row) * NH2 + k0 + ssl * 8],
                        &Asm[wid * 512]);
        }
        // B: 96 stripes, wave w -> stripes 12w..12w+11
        #pragma unroll
        for (int i = 0; i < 12; ++i) {
            const int stripe = wid * 12 + i;
            const int row    = stripe * 8 + srow;
            gload_lds16(&Wat[(size_t)row * NH2 + k0 + ssl * 8],
                        &Bsm[stripe * 512]);
        }
        __syncthreads();

        #pragma unroll
        for (int kk = 0; kk < 2; ++kk) {
            const int slot = kk * 4 + sl0;
            bf16x8 af[2], bfr[12];
            #pragma unroll
            for (int m = 0; m < 2; ++m) {
                const int R = wm * 32 + m * 16 + l16;
                af[m] = *(const bf16x8*)&Asm[R * 64 + (slot ^ (R & 7)) * 8];
            }
            #pragma unroll
            for (int n = 0; n < 12; ++n) {
                const int R = wn * 192 + n * 16 + l16;
                bfr[n] = *(const bf16x8*)&Bsm[R * 64 + (slot ^ (R & 7)) * 8];
            }
            #pragma unroll
            for (int m = 0; m < 2; ++m)
                #pragma unroll
                for (int n = 0; n < 12; ++n)
                    acc[m][n] = __builtin_amdgcn_mfma_f32_16x16x32_bf16(
                        af[m], bfr[n], acc[m][n], 0, 0, 0);
        }
    }

    // bias
    float bb[12];
    #pragma unroll
    for (int n = 0; n < 12; ++n) bb[n] = ba[wn * 192 + n * 16 + l16];
    #pragma unroll
    for (int m = 0; m < 2; ++m)
        #pragma unroll
        for (int n = 0; n < 12; ++n)
            #pragma unroll
            for (int j = 0; j < 4; ++j) acc[m][n][j] += bb[n];

    // row max
    #pragma unroll
    for (int m = 0; m < 2; ++m)
        #pragma unroll
        for (int j = 0; j < 4; ++j) {
            float p = acc[m][0][j];
            #pragma unroll
            for (int n = 1; n < 12; ++n) p = fmaxf(p, acc[m][n][j]);
            #pragma unroll
            for (int off = 8; off; off >>= 1) p = fmaxf(p, __shfl_xor(p, off));
            if (l16 == 0) red[wid][wm * 32 + m * 16 + g4 + j] = p;
        }
    __syncthreads();
    if (t < 64) {
        const int w0 = (t >> 5) * 4;
        stats[t] = fmaxf(fmaxf(red[w0][t], red[w0 + 1][t]),
                         fmaxf(red[w0 + 2][t], red[w0 + 3][t]));
    }
    __syncthreads();
    // exp + row sum
    #pragma unroll
    for (int m = 0; m < 2; ++m)
        #pragma unroll
        for (int j = 0; j < 4; ++j) {
            float M = stats[wm * 32 + m * 16 + g4 + j];
            float s = 0.f;
            #pragma unroll
            for (int n = 0; n < 12; ++n) {
                acc[m][n][j] = __expf(acc[m][n][j] - M);
                s += acc[m][n][j];
            }
            #pragma unroll
            for (int off = 8; off; off >>= 1) s += __shfl_xor(s, off);
            if (l16 == 0) red[wid][wm * 32 + m * 16 + g4 + j] = s;
        }
    __syncthreads();
    if (t < 64) {
        const int w0 = (t >> 5) * 4;
        stats[t] = 1.f / (red[w0][t] + red[w0 + 1][t] + red[w0 + 2][t] + red[w0 + 3][t]);
    }
    __syncthreads();

    // staged fp32 output, two 32-row passes (stride 768 floats, fits Bsm)
    float* stage = (float*)Bsm;
    #pragma unroll
    for (int h = 0; h < 2; ++h) {
        if (wm == h) {
            #pragma unroll
            for (int m = 0; m < 2; ++m)
                #pragma unroll
                for (int j = 0; j < 4; ++j) {
                    const int r = m * 16 + g4 + j;
                    const float inv = stats[h * 32 + r];
                    #pragma unroll
                    for (int n = 0; n < 12; ++n)
                        stage[r * 768 + wn * 192 + n * 16 + l16] = acc[m][n][j] * inv;
                }
        }
        __syncthreads();
        #pragma unroll
        for (int i = 0; i < 12; ++i) {
            int ch  = t + i * 512;          // 6144 chunks of 16 B
            int row = ch / 192;
            int q   = ch - row * 192;
            *(float4*)&attn[(size_t)(rb + h * 32 + row) * DD + q * 4] =
                *(const float4*)&stage[row * 768 + q * 4];
        }
        __syncthreads();
    }
}

// ---------------------------------------------------------------------------
// k4: per row: W = Wflat_bf16 * attn; modified Gram-Schmidt; normalize.
__global__ __launch_bounds__(256) void k_gs(float* __restrict__ out)
{
    const int wid  = threadIdx.x >> 6;
    const int lane = threadIdx.x & 63;
    const size_t row = (size_t)blockIdx.x * 4 + wid;

    float* Wf = out + row * (KK * DD);
    const ushort* wsrc = (const ushort*)out + row * 6144 + 3072;
    const float* at = out + (size_t)BSZ * (KK * DD) + row * DD;

    float a[12];
    #pragma unroll
    for (int k = 0; k < 3; ++k) {
        float4 av = *(const float4*)&at[lane * 4 + 256 * k];
        a[k * 4 + 0] = av.x; a[k * 4 + 1] = av.y;
        a[k * 4 + 2] = av.z; a[k * 4 + 3] = av.w;
    }
    float w[4][12];
    #pragma unroll
    for (int i = 0; i < 4; ++i) {
        #pragma unroll
        for (int k = 0; k < 3; ++k) {
            ushort4 uv = *(const ushort4*)&wsrc[i * DD + lane * 4 + 256 * k];
            w[i][k * 4 + 0] = bf2f(uv.x) * a[k * 4 + 0];
            w[i][k * 4 + 1] = bf2f(uv.y) * a[k * 4 + 1];
            w[i][k * 4 + 2] = bf2f(uv.z) * a[k * 4 + 2];
            w[i][k * 4 + 3] = bf2f(uv.w) * a[k * 4 + 3];
        }
    }
    #pragma unroll
    for (int i = 0; i < 4; ++i) {
        #pragma unroll
        for (int p = 0; p < i; ++p) {
            float s = 0.f;
            #pragma unroll
            for (int j = 0; j < 12; ++j) s = fmaf(w[i][j], w[p][j], s);
            #pragma unroll
            for (int off = 32; off; off >>= 1) s += __shfl_xor(s, off);
            #pragma unroll
            for (int j = 0; j < 12; ++j) w[i][j] = fmaf(-s, w[p][j], w[i][j]);
        }
        float n2 = 0.f;
        #pragma unroll
        for (int j = 0; j < 12; ++j) n2 = fmaf(w[i][j], w[i][j], n2);
        #pragma unroll
        for (int off = 32; off; off >>= 1) n2 += __shfl_xor(n2, off);
        float inv = 1.f / fmaxf(sqrtf(n2), 1e-12f);
        #pragma unroll
        for (int j = 0; j < 12; ++j) w[i][j] *= inv;
    }
    #pragma unroll
    for (int i = 0; i < 4; ++i) {
        #pragma unroll
        for (int k = 0; k < 3; ++k) {
            float4 wv;
            wv.x = w[i][k * 4 + 0]; wv.y = w[i][k * 4 + 1];
            wv.z = w[i][k * 4 + 2]; wv.w = w[i][k * 4 + 3];
            *(float4*)&Wf[i * DD + lane * 4 + 256 * k] = wv;
        }
    }
}

// ---------------------------------------------------------------------------
extern "C" void kernel_launch(void* const* d_in, const int* in_sizes, int n_in,
                              void* d_out, int out_size, void* d_ws, size_t ws_size,
                              hipStream_t stream)
{
    const float* emb = (const float*)d_in[0];
    const float* W1  = (const float*)d_in[1];
    const float* b1  = (const float*)d_in[2];
    const float* g1  = (const float*)d_in[3];
    const float* be1 = (const float*)d_in[4];
    const float* W2  = (const float*)d_in[5];
    const float* b2  = (const float*)d_in[6];
    const float* g2  = (const float*)d_in[7];
    const float* be2 = (const float*)d_in[8];
    const float* Wd  = (const float*)d_in[9];
    const float* bd  = (const float*)d_in[10];
    const float* Wa  = (const float*)d_in[11];
    const float* ba  = (const float*)d_in[12];

    float* out = (float*)d_out;
    ushort* h1   = (ushort*)d_ws;                // B*512 bf16 = 16.8 MB
    ushort* h2   = h1 + (size_t)BSZ * NH1;       // B*256 bf16 =  8.4 MB
    ushort* Wdt  = h2 + (size_t)BSZ * NH2;       // 3072*256 bf16 = 1.5 MB
    ushort* W1t  = Wdt + (size_t)ND * NH2;       // 512*768 bf16 = 0.77 MB
    ushort* W2t  = W1t + (size_t)NH1 * DD;       // 256*512 bf16 = 0.25 MB
    ushort* Wat  = W2t + (size_t)NH2 * NH1;      // 768*256 bf16 = 0.39 MB
    ushort* embb = Wat + (size_t)DD * NH2;       // B*768 bf16 = 25.2 MB
    float* attn = out + (size_t)BSZ * KK * DD;   // attn region of out, B*D

    hipLaunchKernelGGL(k_cvt_emb, dim3(2048), dim3(256), 0, stream,
                       emb, embb, BSZ * DD / 8);
    hipLaunchKernelGGL(k_t_cvt, dim3(NH1 / 32, DD / 32), dim3(256), 0, stream,
                       W1, W1t, DD, NH1);        // W1 (768x512) -> W1t (512x768)
    hipLaunchKernelGGL(k_t_cvt, dim3(NH2 / 32, NH1 / 32), dim3(256), 0, stream,
                       W2, W2t, NH1, NH2);       // W2 (512x256) -> W2t (256x512)
    hipLaunchKernelGGL(k_t_cvt, dim3(ND / 32, NH2 / 32), dim3(256), 0, stream,
                       Wd, Wdt, NH2, ND);        // Wd (256x3072) -> Wdt (3072x256)
    hipLaunchKernelGGL(k_t_cvt, dim3(DD / 32, NH2 / 32), dim3(256), 0, stream,
                       Wa, Wat, NH2, DD);        // Wa (256x768) -> Wat (768x256)
    hipLaunchKernelGGL(k1_gemm, dim3(NH1 / 128, BSZ / 128), dim3(256), 0, stream,
                       embb, W1t, b1, h1);
    hipLaunchKernelGGL(k1_ln, dim3(BSZ / 4), dim3(256), 0, stream,
                       h1, g1, be1);
    hipLaunchKernelGGL(k2_mfma, dim3(BSZ / 64), dim3(512), 0, stream,
                       h1, W2t, b2, g2, be2, h2);
    hipLaunchKernelGGL(k_gemm_wd_mfma, dim3(ND / 128, BSZ / 128), dim3(256), 0, stream,
                       h2, Wdt, bd, (ushort*)out);
    hipLaunchKernelGGL(k_attn_mfma, dim3(BSZ / 64), dim3(512), 0, stream,
                       h2, Wat, ba, attn);
    hipLaunchKernelGGL(k_gs, dim3(BSZ / 4), dim3(256), 0, stream, out);
}

// Round 12
// 181.502 us; speedup vs baseline: 1.9983x; 1.0406x over previous
//
#include <hip/hip_runtime.h>
#include <hip/hip_bf16.h>

#define BSZ 16384
#define DD  768
#define KK  4
#define NH1 512
#define NH2 256
#define ND  (KK * DD)   // 3072

typedef __bf16 bf16x8 __attribute__((ext_vector_type(8)));
typedef float  f32x4  __attribute__((ext_vector_type(4)));

static __device__ __forceinline__ float bf2f(ushort u) {
    union { unsigned int i; float f; } v; v.i = (unsigned int)u << 16; return v.f;
}
static __device__ __forceinline__ ushort f2bf(float f) {
    return __bfloat16_as_ushort(__float2bfloat16(f));
}
// async global->LDS, 16B per lane; LDS dest = uniform base + lane*16
static __device__ __forceinline__ void gload_lds16(const void* g, void* l) {
    __builtin_amdgcn_global_load_lds(
        (const __attribute__((address_space(1))) void*)g,
        (__attribute__((address_space(3))) void*)l, 16, 0, 0);
}

// ---------------------------------------------------------------------------
// k_cvt_emb: emb fp32 -> bf16, row-major copy-convert (8 elems/thread/iter)
__global__ __launch_bounds__(256) void k_cvt_emb(
    const float* __restrict__ src, ushort* __restrict__ dst, int n8)
{
    const int stride = gridDim.x * 256;
    for (int i = blockIdx.x * 256 + threadIdx.x; i < n8; i += stride) {
        float4 a = *(const float4*)&src[(size_t)i * 8];
        float4 b = *(const float4*)&src[(size_t)i * 8 + 4];
        ushort u[8];
        u[0] = f2bf(a.x); u[1] = f2bf(a.y); u[2] = f2bf(a.z); u[3] = f2bf(a.w);
        u[4] = f2bf(b.x); u[5] = f2bf(b.y); u[6] = f2bf(b.z); u[7] = f2bf(b.w);
        *(int4*)&dst[(size_t)i * 8] = *(int4*)u;
    }
}

// ---------------------------------------------------------------------------
// k_t_cvt: src (R x C f32) -> dst (C x R bf16)  [generic transpose+convert]
__global__ __launch_bounds__(256) void k_t_cvt(
    const float* __restrict__ src, ushort* __restrict__ dst, int R, int C)
{
    __shared__ float tile[32][33];
    const int rb0 = blockIdx.y * 32;  // src row
    const int cb0 = blockIdx.x * 32;  // src col
    const int t = threadIdx.x;
    const int r = t >> 5, c = t & 31;
    #pragma unroll
    for (int i = 0; i < 4; ++i)
        tile[r + i * 8][c] = src[(size_t)(rb0 + r + i * 8) * C + cb0 + c];
    __syncthreads();
    #pragma unroll
    for (int i = 0; i < 4; ++i)
        dst[(size_t)(cb0 + r + i * 8) * R + rb0 + c] = f2bf(tile[c][r + i * 8]);
}

// ---------------------------------------------------------------------------
// k1_gemm: h1_raw = embb @ W1 + b1 (bf16). 128x128 tile, BK=64, 12 K-steps.
// global_load_lds(16B) staging, linear [128][64] LDS, both-sides XOR swizzle.
__global__ __launch_bounds__(256) void k1_gemm(
    const ushort* __restrict__ embb, const ushort* __restrict__ W1t,
    const float* __restrict__ b1, ushort* __restrict__ h1raw)
{
    __shared__ ushort smem[2 * 128 * 64];   // Asm | Bsm = 32 KB; reused for C-stage
    ushort* Asm = smem;
    ushort* Bsm = smem + 128 * 64;

    const int t    = threadIdx.x;
    const int lane = t & 63;
    const int wid  = t >> 6;
    const int wm   = wid >> 1;
    const int wn   = wid & 1;
    const int l16  = lane & 15;
    const int sl0  = lane >> 4;         // 0..3: 16B slot base within K-half
    const int g4   = (lane >> 4) * 4;

    const int srow = lane >> 3;         // staging: row within 8-row stripe
    const int ssl  = (lane & 7) ^ srow; // staging: swizzled k-slot

    const int rb = blockIdx.y * 128;    // M tile
    const int cb = blockIdx.x * 128;    // N tile (over NH1=512)

    f32x4 acc[4][4] = {};

    for (int ks = 0; ks < 12; ++ks) {
        const int k0 = ks * 64;
        __syncthreads();   // prior MFMA reads done before LDS overwrite
        #pragma unroll
        for (int i = 0; i < 4; ++i) {
            const int stripe = wid * 4 + i;         // 0..15
            const int row    = stripe * 8 + srow;
            gload_lds16(&embb[(size_t)(rb + row) * DD + k0 + ssl * 8],
                        &Asm[stripe * 512]);
            gload_lds16(&W1t [(size_t)(cb + row) * DD + k0 + ssl * 8],
                        &Bsm[stripe * 512]);
        }
        __syncthreads();   // vmcnt(0) drain + barrier -> staged visible

        #pragma unroll
        for (int kk = 0; kk < 2; ++kk) {
            const int slot = kk * 4 + sl0;          // 0..7
            bf16x8 af[4], bfr[4];
            #pragma unroll
            for (int m = 0; m < 4; ++m) {
                const int R = wm * 64 + m * 16 + l16;
                af[m] = *(const bf16x8*)&Asm[R * 64 + (slot ^ (R & 7)) * 8];
            }
            #pragma unroll
            for (int n = 0; n < 4; ++n) {
                const int R = wn * 64 + n * 16 + l16;
                bfr[n] = *(const bf16x8*)&Bsm[R * 64 + (slot ^ (R & 7)) * 8];
            }
            #pragma unroll
            for (int m = 0; m < 4; ++m)
                #pragma unroll
                for (int n = 0; n < 4; ++n)
                    acc[m][n] = __builtin_amdgcn_mfma_f32_16x16x32_bf16(
                        af[m], bfr[n], acc[m][n], 0, 0, 0);
        }
    }

    float bv[4];
    #pragma unroll
    for (int n = 0; n < 4; ++n)
        bv[n] = b1[cb + wn * 64 + n * 16 + l16];

    __syncthreads();
    #pragma unroll
    for (int m = 0; m < 4; ++m)
        #pragma unroll
        for (int n = 0; n < 4; ++n)
            #pragma unroll
            for (int j = 0; j < 4; ++j)
                smem[(wm * 64 + m * 16 + g4 + j) * 128 + wn * 64 + n * 16 + l16] =
                    f2bf(acc[m][n][j] + bv[n]);
    __syncthreads();
    #pragma unroll
    for (int i = 0; i < 8; ++i) {
        int ch  = t + i * 256;              // 2048 chunks of 16 B
        int row = ch >> 4;
        int q   = ch & 15;
        *(int4*)&h1raw[(size_t)(rb + row) * NH1 + cb + q * 8] =
            *(const int4*)&smem[row * 128 + q * 8];
    }
}

// ---------------------------------------------------------------------------
// k1_ln: in-place LN+relu over h1 rows (512 bf16). One wave per row.
__global__ __launch_bounds__(256) void k1_ln(
    ushort* h1, const float* __restrict__ g1, const float* __restrict__ be1)
{
    const int lane = threadIdx.x & 63;
    const int w    = threadIdx.x >> 6;
    const size_t row = (size_t)blockIdx.x * 4 + w;

    ushort* p = h1 + row * NH1 + lane * 8;
    ushort u[8];
    *(int4*)u = *(const int4*)p;
    float x[8];
    float s = 0.f, q = 0.f;
    #pragma unroll
    for (int j = 0; j < 8; ++j) {
        x[j] = bf2f(u[j]);
        s += x[j];
        q += x[j] * x[j];
    }
    #pragma unroll
    for (int off = 32; off; off >>= 1) {
        s += __shfl_xor(s, off);
        q += __shfl_xor(q, off);
    }
    const float mu  = s * (1.f / NH1);
    const float var = q * (1.f / NH1) - mu * mu;
    const float rs  = rsqrtf(var + 1e-5f);

    float gv[8], ev[8];
    *(float4*)&gv[0] = *(const float4*)&g1[lane * 8];
    *(float4*)&gv[4] = *(const float4*)&g1[lane * 8 + 4];
    *(float4*)&ev[0] = *(const float4*)&be1[lane * 8];
    *(float4*)&ev[4] = *(const float4*)&be1[lane * 8 + 4];
    #pragma unroll
    for (int j = 0; j < 8; ++j)
        u[j] = f2bf(fmaxf(fmaf((x[j] - mu) * rs, gv[j], ev[j]), 0.f));
    *(int4*)p = *(int4*)u;
}

// ---------------------------------------------------------------------------
// k2 (MFMA, fused LN+relu): h2 = relu(LN(h1 @ W2 + b2)) stored bf16.
// global_load_lds staging, linear [64][64]/[256][64] LDS + swizzle.
__global__ __launch_bounds__(512) void k2_mfma(
    const ushort* __restrict__ h1, const ushort* __restrict__ W2t,
    const float* __restrict__ b2, const float* __restrict__ g2,
    const float* __restrict__ be2, ushort* __restrict__ h2)
{
    __shared__ ushort Asm[64 * 64];     //  8 KB
    __shared__ ushort Bsm[256 * 64];    // 32 KB
    __shared__ float red[8][64][2];
    __shared__ float stats[64][2];

    const int t    = threadIdx.x;
    const int lane = t & 63;
    const int wid  = t >> 6;            // 0..7
    const int wm   = wid >> 2;          // 0..1
    const int wn   = wid & 3;           // 0..3
    const int l16  = lane & 15;
    const int sl0  = lane >> 4;
    const int g4   = (lane >> 4) * 4;
    const int rb   = blockIdx.x * 64;

    const int srow = lane >> 3;
    const int ssl  = (lane & 7) ^ srow;

    f32x4 acc[2][4] = {};

    for (int ks = 0; ks < 8; ++ks) {
        const int k0 = ks * 64;
        __syncthreads();
        {
            const int row = wid * 8 + srow;
            gload_lds16(&h1[(size_t)(rb + row) * NH1 + k0 + ssl * 8],
                        &Asm[wid * 512]);
        }
        #pragma unroll
        for (int i = 0; i < 4; ++i) {
            const int stripe = wid * 4 + i;
            const int row    = stripe * 8 + srow;
            gload_lds16(&W2t[(size_t)row * NH1 + k0 + ssl * 8],
                        &Bsm[stripe * 512]);
        }
        __syncthreads();

        #pragma unroll
        for (int kk = 0; kk < 2; ++kk) {
            const int slot = kk * 4 + sl0;
            bf16x8 af[2], bfr[4];
            #pragma unroll
            for (int m = 0; m < 2; ++m) {
                const int R = wm * 32 + m * 16 + l16;
                af[m] = *(const bf16x8*)&Asm[R * 64 + (slot ^ (R & 7)) * 8];
            }
            #pragma unroll
            for (int n = 0; n < 4; ++n) {
                const int R = wn * 64 + n * 16 + l16;
                bfr[n] = *(const bf16x8*)&Bsm[R * 64 + (slot ^ (R & 7)) * 8];
            }
            #pragma unroll
            for (int m = 0; m < 2; ++m)
                #pragma unroll
                for (int n = 0; n < 4; ++n)
                    acc[m][n] = __builtin_amdgcn_mfma_f32_16x16x32_bf16(
                        af[m], bfr[n], acc[m][n], 0, 0, 0);
        }
    }

    float bv[4];
    #pragma unroll
    for (int n = 0; n < 4; ++n) bv[n] = b2[wn * 64 + n * 16 + l16];
    #pragma unroll
    for (int m = 0; m < 2; ++m)
        #pragma unroll
        for (int n = 0; n < 4; ++n)
            #pragma unroll
            for (int j = 0; j < 4; ++j) acc[m][n][j] += bv[n];

    #pragma unroll
    for (int m = 0; m < 2; ++m)
        #pragma unroll
        for (int j = 0; j < 4; ++j) {
            float p = 0.f, q = 0.f;
            #pragma unroll
            for (int n = 0; n < 4; ++n) {
                float v = acc[m][n][j];
                p += v; q += v * v;
            }
            #pragma unroll
            for (int off = 8; off; off >>= 1) {
                p += __shfl_xor(p, off);
                q += __shfl_xor(q, off);
            }
            if (l16 == 0) {
                red[wid][wm * 32 + m * 16 + g4 + j][0] = p;
                red[wid][wm * 32 + m * 16 + g4 + j][1] = q;
            }
        }
    __syncthreads();
    if (t < 64) {
        const int w0 = (t >> 5) * 4;
        float S = 0.f, S2 = 0.f;
        #pragma unroll
        for (int w = 0; w < 4; ++w) { S += red[w0 + w][t][0]; S2 += red[w0 + w][t][1]; }
        float mu  = S  * (1.f / NH2);
        float var = S2 * (1.f / NH2) - mu * mu;
        stats[t][0] = mu;
        stats[t][1] = rsqrtf(var + 1e-5f);
    }
    __syncthreads();

    float gv[4], ev[4];
    #pragma unroll
    for (int n = 0; n < 4; ++n) {
        int col = wn * 64 + n * 16 + l16;
        gv[n] = g2[col]; ev[n] = be2[col];
    }
    ushort* dst = h2 + (size_t)rb * NH2;
    #pragma unroll
    for (int m = 0; m < 2; ++m)
        #pragma unroll
        for (int j = 0; j < 4; ++j) {
            int row = wm * 32 + m * 16 + g4 + j;
            float mu = stats[row][0], rs = stats[row][1];
            #pragma unroll
            for (int n = 0; n < 4; ++n) {
                float val = fmaxf(fmaf((acc[m][n][j] - mu) * rs, gv[n], ev[n]), 0.f);
                dst[(size_t)row * NH2 + wn * 64 + n * 16 + l16] = f2bf(val);
            }
        }
}

// ---------------------------------------------------------------------------
// k3a: W_flat(bf16) = h2 @ Wd + bd, packed into second half of out rows.
// global_load_lds + XOR-swizzle staging.
__global__ __launch_bounds__(256) void k_gemm_wd_mfma(
    const ushort* __restrict__ h2, const ushort* __restrict__ Wdt,
    const float* __restrict__ bd, ushort* __restrict__ outw)
{
    __shared__ ushort smem[2 * 128 * 64];   // Asm | Bsm = 32 KB; reused for C-stage
    ushort* Asm = smem;
    ushort* Bsm = smem + 128 * 64;

    const int t    = threadIdx.x;
    const int lane = t & 63;
    const int wid  = t >> 6;
    const int wm   = wid >> 1;
    const int wn   = wid & 1;
    const int l16  = lane & 15;
    const int sl0  = lane >> 4;
    const int g4   = (lane >> 4) * 4;

    const int srow = lane >> 3;
    const int ssl  = (lane & 7) ^ srow;

    const int rb = blockIdx.y * 128;
    const int cb = blockIdx.x * 128;

    f32x4 acc[4][4] = {};

    for (int ks = 0; ks < 4; ++ks) {
        const int k0 = ks * 64;
        __syncthreads();
        #pragma unroll
        for (int i = 0; i < 4; ++i) {
            const int stripe = wid * 4 + i;
            const int row    = stripe * 8 + srow;
            gload_lds16(&h2 [(size_t)(rb + row) * NH2 + k0 + ssl * 8],
                        &Asm[stripe * 512]);
            gload_lds16(&Wdt[(size_t)(cb + row) * NH2 + k0 + ssl * 8],
                        &Bsm[stripe * 512]);
        }
        __syncthreads();

        #pragma unroll
        for (int kk = 0; kk < 2; ++kk) {
            const int slot = kk * 4 + sl0;
            bf16x8 af[4], bfr[4];
            #pragma unroll
            for (int m = 0; m < 4; ++m) {
                const int R = wm * 64 + m * 16 + l16;
                af[m] = *(const bf16x8*)&Asm[R * 64 + (slot ^ (R & 7)) * 8];
            }
            #pragma unroll
            for (int n = 0; n < 4; ++n) {
                const int R = wn * 64 + n * 16 + l16;
                bfr[n] = *(const bf16x8*)&Bsm[R * 64 + (slot ^ (R & 7)) * 8];
            }
            #pragma unroll
            for (int m = 0; m < 4; ++m)
                #pragma unroll
                for (int n = 0; n < 4; ++n)
                    acc[m][n] = __builtin_amdgcn_mfma_f32_16x16x32_bf16(
                        af[m], bfr[n], acc[m][n], 0, 0, 0);
        }
    }

    float bv[4];
    #pragma unroll
    for (int n = 0; n < 4; ++n)
        bv[n] = bd[cb + wn * 64 + n * 16 + l16];

    __syncthreads();
    #pragma unroll
    for (int m = 0; m < 4; ++m)
        #pragma unroll
        for (int n = 0; n < 4; ++n)
            #pragma unroll
            for (int j = 0; j < 4; ++j)
                smem[(wm * 64 + m * 16 + g4 + j) * 128 + wn * 64 + n * 16 + l16] =
                    f2bf(acc[m][n][j] + bv[n]);
    __syncthreads();
    #pragma unroll
    for (int i = 0; i < 8; ++i) {
        int ch  = t + i * 256;
        int row = ch >> 4;
        int q   = ch & 15;
        *(int4*)&outw[(size_t)(rb + row) * 6144 + 3072 + cb + q * 8] =
            *(const int4*)&smem[row * 128 + q * 8];
    }
}

// ---------------------------------------------------------------------------
// k3b (MFMA, fused softmax + Gram-Schmidt): attn = softmax(h2 @ Wa + ba);
// then per row W = Wflat_bf16 * attn, modified GS, normalize -> out.
// Round-12: absorbs k_gs. After each 32-row stage pass, 8 waves x 4 rows
// read attn from stage LDS + W bf16 from out, orthogonalize in regs, write.
__global__ __launch_bounds__(512) void k_attn_gs_mfma(
    const ushort* __restrict__ h2, const ushort* __restrict__ Wat,
    const float* __restrict__ ba, float* __restrict__ out)
{
    __shared__ ushort Asm[64 * 64];      //  8 KB
    __shared__ ushort Bsm[768 * 64];     // 96 KB (reused as f32 stage [32][768])
    __shared__ float red[8][64];
    __shared__ float stats[64];

    const int t    = threadIdx.x;
    const int lane = t & 63;
    const int wid  = t >> 6;            // 0..7
    const int wm   = wid >> 2;          // 0..1
    const int wn   = wid & 3;           // 0..3
    const int l16  = lane & 15;
    const int sl0  = lane >> 4;
    const int g4   = (lane >> 4) * 4;
    const int rb   = blockIdx.x * 64;

    const int srow = lane >> 3;
    const int ssl  = (lane & 7) ^ srow;

    float* attn = out + (size_t)BSZ * (KK * DD);

    f32x4 acc[2][12] = {};

    for (int ks = 0; ks < 4; ++ks) {
        const int k0 = ks * 64;
        __syncthreads();
        {
            const int row = wid * 8 + srow;
            gload_lds16(&h2[(size_t)(rb + row) * NH2 + k0 + ssl * 8],
                        &Asm[wid * 512]);
        }
        #pragma unroll
        for (int i = 0; i < 12; ++i) {
            const int stripe = wid * 12 + i;
            const int row    = stripe * 8 + srow;
            gload_lds16(&Wat[(size_t)row * NH2 + k0 + ssl * 8],
                        &Bsm[stripe * 512]);
        }
        __syncthreads();

        #pragma unroll
        for (int kk = 0; kk < 2; ++kk) {
            const int slot = kk * 4 + sl0;
            bf16x8 af[2], bfr[12];
            #pragma unroll
            for (int m = 0; m < 2; ++m) {
                const int R = wm * 32 + m * 16 + l16;
                af[m] = *(const bf16x8*)&Asm[R * 64 + (slot ^ (R & 7)) * 8];
            }
            #pragma unroll
            for (int n = 0; n < 12; ++n) {
                const int R = wn * 192 + n * 16 + l16;
                bfr[n] = *(const bf16x8*)&Bsm[R * 64 + (slot ^ (R & 7)) * 8];
            }
            #pragma unroll
            for (int m = 0; m < 2; ++m)
                #pragma unroll
                for (int n = 0; n < 12; ++n)
                    acc[m][n] = __builtin_amdgcn_mfma_f32_16x16x32_bf16(
                        af[m], bfr[n], acc[m][n], 0, 0, 0);
        }
    }

    // bias
    float bb[12];
    #pragma unroll
    for (int n = 0; n < 12; ++n) bb[n] = ba[wn * 192 + n * 16 + l16];
    #pragma unroll
    for (int m = 0; m < 2; ++m)
        #pragma unroll
        for (int n = 0; n < 12; ++n)
            #pragma unroll
            for (int j = 0; j < 4; ++j) acc[m][n][j] += bb[n];

    // row max
    #pragma unroll
    for (int m = 0; m < 2; ++m)
        #pragma unroll
        for (int j = 0; j < 4; ++j) {
            float p = acc[m][0][j];
            #pragma unroll
            for (int n = 1; n < 12; ++n) p = fmaxf(p, acc[m][n][j]);
            #pragma unroll
            for (int off = 8; off; off >>= 1) p = fmaxf(p, __shfl_xor(p, off));
            if (l16 == 0) red[wid][wm * 32 + m * 16 + g4 + j] = p;
        }
    __syncthreads();
    if (t < 64) {
        const int w0 = (t >> 5) * 4;
        stats[t] = fmaxf(fmaxf(red[w0][t], red[w0 + 1][t]),
                         fmaxf(red[w0 + 2][t], red[w0 + 3][t]));
    }
    __syncthreads();
    // exp + row sum
    #pragma unroll
    for (int m = 0; m < 2; ++m)
        #pragma unroll
        for (int j = 0; j < 4; ++j) {
            float M = stats[wm * 32 + m * 16 + g4 + j];
            float s = 0.f;
            #pragma unroll
            for (int n = 0; n < 12; ++n) {
                acc[m][n][j] = __expf(acc[m][n][j] - M);
                s += acc[m][n][j];
            }
            #pragma unroll
            for (int off = 8; off; off >>= 1) s += __shfl_xor(s, off);
            if (l16 == 0) red[wid][wm * 32 + m * 16 + g4 + j] = s;
        }
    __syncthreads();
    if (t < 64) {
        const int w0 = (t >> 5) * 4;
        stats[t] = 1.f / (red[w0][t] + red[w0 + 1][t] + red[w0 + 2][t] + red[w0 + 3][t]);
    }
    __syncthreads();

    // two 32-row passes: stage scaled attn -> write attn -> GS those rows
    float* stage = (float*)Bsm;
    #pragma unroll
    for (int h = 0; h < 2; ++h) {
        if (wm == h) {
            #pragma unroll
            for (int m = 0; m < 2; ++m)
                #pragma unroll
                for (int j = 0; j < 4; ++j) {
                    const int r = m * 16 + g4 + j;
                    const float inv = stats[h * 32 + r];
                    #pragma unroll
                    for (int n = 0; n < 12; ++n)
                        stage[r * 768 + wn * 192 + n * 16 + l16] = acc[m][n][j] * inv;
                }
        }
        __syncthreads();
        // coalesced attn output
        #pragma unroll
        for (int i = 0; i < 12; ++i) {
            int ch  = t + i * 512;          // 6144 chunks of 16 B
            int row = ch / 192;
            int q   = ch - row * 192;
            *(float4*)&attn[(size_t)(rb + h * 32 + row) * DD + q * 4] =
                *(const float4*)&stage[row * 768 + q * 4];
        }
        // Gram-Schmidt: wave wid owns rows wid*4 .. wid*4+3 of this half
        for (int rr = 0; rr < 4; ++rr) {
            const int rl = wid * 4 + rr;
            const size_t row = (size_t)rb + h * 32 + rl;
            float a[12];
            #pragma unroll
            for (int k = 0; k < 3; ++k)
                *(float4*)&a[k * 4] =
                    *(const float4*)&stage[rl * 768 + lane * 4 + 256 * k];

            const ushort* wsrc = (const ushort*)out + row * 6144 + 3072;
            float* Wf = out + row * (KK * DD);
            float w[4][12];
            #pragma unroll
            for (int i = 0; i < 4; ++i) {
                #pragma unroll
                for (int k = 0; k < 3; ++k) {
                    ushort4 uv = *(const ushort4*)&wsrc[i * DD + lane * 4 + 256 * k];
                    w[i][k * 4 + 0] = bf2f(uv.x) * a[k * 4 + 0];
                    w[i][k * 4 + 1] = bf2f(uv.y) * a[k * 4 + 1];
                    w[i][k * 4 + 2] = bf2f(uv.z) * a[k * 4 + 2];
                    w[i][k * 4 + 3] = bf2f(uv.w) * a[k * 4 + 3];
                }
            }
            #pragma unroll
            for (int i = 0; i < 4; ++i) {
                #pragma unroll
                for (int p = 0; p < i; ++p) {
                    float s2 = 0.f;
                    #pragma unroll
                    for (int j = 0; j < 12; ++j) s2 = fmaf(w[i][j], w[p][j], s2);
                    #pragma unroll
                    for (int off = 32; off; off >>= 1) s2 += __shfl_xor(s2, off);
                    #pragma unroll
                    for (int j = 0; j < 12; ++j) w[i][j] = fmaf(-s2, w[p][j], w[i][j]);
                }
                float n2 = 0.f;
                #pragma unroll
                for (int j = 0; j < 12; ++j) n2 = fmaf(w[i][j], w[i][j], n2);
                #pragma unroll
                for (int off = 32; off; off >>= 1) n2 += __shfl_xor(n2, off);
                float invn = 1.f / fmaxf(sqrtf(n2), 1e-12f);
                #pragma unroll
                for (int j = 0; j < 12; ++j) w[i][j] *= invn;
            }
            #pragma unroll
            for (int i = 0; i < 4; ++i) {
                #pragma unroll
                for (int k = 0; k < 3; ++k) {
                    float4 wv;
                    wv.x = w[i][k * 4 + 0]; wv.y = w[i][k * 4 + 1];
                    wv.z = w[i][k * 4 + 2]; wv.w = w[i][k * 4 + 3];
                    *(float4*)&Wf[i * DD + lane * 4 + 256 * k] = wv;
                }
            }
        }
        __syncthreads();    // stage reads done before next half overwrites
    }
}

// ---------------------------------------------------------------------------
extern "C" void kernel_launch(void* const* d_in, const int* in_sizes, int n_in,
                              void* d_out, int out_size, void* d_ws, size_t ws_size,
                              hipStream_t stream)
{
    const float* emb = (const float*)d_in[0];
    const float* W1  = (const float*)d_in[1];
    const float* b1  = (const float*)d_in[2];
    const float* g1  = (const float*)d_in[3];
    const float* be1 = (const float*)d_in[4];
    const float* W2  = (const float*)d_in[5];
    const float* b2  = (const float*)d_in[6];
    const float* g2  = (const float*)d_in[7];
    const float* be2 = (const float*)d_in[8];
    const float* Wd  = (const float*)d_in[9];
    const float* bd  = (const float*)d_in[10];
    const float* Wa  = (const float*)d_in[11];
    const float* ba  = (const float*)d_in[12];

    float* out = (float*)d_out;
    ushort* h1   = (ushort*)d_ws;                // B*512 bf16 = 16.8 MB
    ushort* h2   = h1 + (size_t)BSZ * NH1;       // B*256 bf16 =  8.4 MB
    ushort* Wdt  = h2 + (size_t)BSZ * NH2;       // 3072*256 bf16 = 1.5 MB
    ushort* W1t  = Wdt + (size_t)ND * NH2;       // 512*768 bf16 = 0.77 MB
    ushort* W2t  = W1t + (size_t)NH1 * DD;       // 256*512 bf16 = 0.25 MB
    ushort* Wat  = W2t + (size_t)NH2 * NH1;      // 768*256 bf16 = 0.39 MB
    ushort* embb = Wat + (size_t)DD * NH2;       // B*768 bf16 = 25.2 MB

    hipLaunchKernelGGL(k_cvt_emb, dim3(2048), dim3(256), 0, stream,
                       emb, embb, BSZ * DD / 8);
    hipLaunchKernelGGL(k_t_cvt, dim3(NH1 / 32, DD / 32), dim3(256), 0, stream,
                       W1, W1t, DD, NH1);        // W1 (768x512) -> W1t (512x768)
    hipLaunchKernelGGL(k_t_cvt, dim3(NH2 / 32, NH1 / 32), dim3(256), 0, stream,
                       W2, W2t, NH1, NH2);       // W2 (512x256) -> W2t (256x512)
    hipLaunchKernelGGL(k_t_cvt, dim3(ND / 32, NH2 / 32), dim3(256), 0, stream,
                       Wd, Wdt, NH2, ND);        // Wd (256x3072) -> Wdt (3072x256)
    hipLaunchKernelGGL(k_t_cvt, dim3(DD / 32, NH2 / 32), dim3(256), 0, stream,
                       Wa, Wat, NH2, DD);        // Wa (256x768) -> Wat (768x256)
    hipLaunchKernelGGL(k1_gemm, dim3(NH1 / 128, BSZ / 128), dim3(256), 0, stream,
                       embb, W1t, b1, h1);
    hipLaunchKernelGGL(k1_ln, dim3(BSZ / 4), dim3(256), 0, stream,
                       h1, g1, be1);
    hipLaunchKernelGGL(k2_mfma, dim3(BSZ / 64), dim3(512), 0, stream,
                       h1, W2t, b2, g2, be2, h2);
    hipLaunchKernelGGL(k_gemm_wd_mfma, dim3(ND / 128, BSZ / 128), dim3(256), 0, stream,
                       h2, Wdt, bd, (ushort*)out);
    hipLaunchKernelGGL(k_attn_gs_mfma, dim3(BSZ / 64), dim3(512), 0, stream,
                       h2, Wat, ba, out);
}

// Round 13
// 173.943 us; speedup vs baseline: 2.0852x; 1.0435x over previous
//
#include <hip/hip_runtime.h>
#include <hip/hip_bf16.h>

#define BSZ 16384
#define DD  768
#define KK  4
#define NH1 512
#define NH2 256
#define ND  (KK * DD)   // 3072

typedef __bf16 bf16x8 __attribute__((ext_vector_type(8)));
typedef float  f32x4  __attribute__((ext_vector_type(4)));

static __device__ __forceinline__ float bf2f(ushort u) {
    union { unsigned int i; float f; } v; v.i = (unsigned int)u << 16; return v.f;
}
static __device__ __forceinline__ ushort f2bf(float f) {
    return __bfloat16_as_ushort(__float2bfloat16(f));
}
// async global->LDS, 16B per lane; LDS dest = uniform base + lane*16
static __device__ __forceinline__ void gload_lds16(const void* g, void* l) {
    __builtin_amdgcn_global_load_lds(
        (const __attribute__((address_space(1))) void*)g,
        (__attribute__((address_space(3))) void*)l, 16, 0, 0);
}

// ---------------------------------------------------------------------------
// k_prep: single launch for emb fp32->bf16 + 4 weight transpose-converts.
// Block ranges: [0,2048) emb; [2048,2432) W1; [2432,2560) W2; [2560,3328) Wd;
// [3328,3520) Wa.
__global__ __launch_bounds__(256) void k_prep(
    const float* __restrict__ emb, ushort* __restrict__ embb,
    const float* __restrict__ W1, ushort* __restrict__ W1t,
    const float* __restrict__ W2, ushort* __restrict__ W2t,
    const float* __restrict__ Wd, ushort* __restrict__ Wdt,
    const float* __restrict__ Wa, ushort* __restrict__ Wat)
{
    __shared__ float tile[32][33];
    const int bid = blockIdx.x;
    const int t = threadIdx.x;

    if (bid < 2048) {
        const int n8 = BSZ * DD / 8;
        const int stride = 2048 * 256;
        for (int i = bid * 256 + t; i < n8; i += stride) {
            float4 a = *(const float4*)&emb[(size_t)i * 8];
            float4 b = *(const float4*)&emb[(size_t)i * 8 + 4];
            ushort u[8];
            u[0] = f2bf(a.x); u[1] = f2bf(a.y); u[2] = f2bf(a.z); u[3] = f2bf(a.w);
            u[4] = f2bf(b.x); u[5] = f2bf(b.y); u[6] = f2bf(b.z); u[7] = f2bf(b.w);
            *(int4*)&embb[(size_t)i * 8] = *(int4*)u;
        }
        return;
    }

    const float* src; ushort* dst; int R, C, rb0, cb0;
    if (bid < 2432)      { int l = bid - 2048; src = W1; dst = W1t; R = DD;  C = NH1;
                           cb0 = (l & 15) * 32; rb0 = (l >> 4) * 32; }
    else if (bid < 2560) { int l = bid - 2432; src = W2; dst = W2t; R = NH1; C = NH2;
                           cb0 = (l & 7) * 32;  rb0 = (l >> 3) * 32; }
    else if (bid < 3328) { int l = bid - 2560; src = Wd; dst = Wdt; R = NH2; C = ND;
                           cb0 = (l % 96) * 32; rb0 = (l / 96) * 32; }
    else                 { int l = bid - 3328; src = Wa; dst = Wat; R = NH2; C = DD;
                           cb0 = (l % 24) * 32; rb0 = (l / 24) * 32; }

    const int r = t >> 5, c = t & 31;
    #pragma unroll
    for (int i = 0; i < 4; ++i)
        tile[r + i * 8][c] = src[(size_t)(rb0 + r + i * 8) * C + cb0 + c];
    __syncthreads();
    #pragma unroll
    for (int i = 0; i < 4; ++i)
        dst[(size_t)(cb0 + r + i * 8) * R + rb0 + c] = f2bf(tile[c][r + i * 8]);
}

// ---------------------------------------------------------------------------
// k1_gemm: h1_raw = embb @ W1 + b1 (bf16). 128x128 tile, BK=64, 12 K-steps.
// global_load_lds(16B) staging, linear [128][64] LDS, both-sides XOR swizzle.
__global__ __launch_bounds__(256) void k1_gemm(
    const ushort* __restrict__ embb, const ushort* __restrict__ W1t,
    const float* __restrict__ b1, ushort* __restrict__ h1raw)
{
    __shared__ ushort smem[2 * 128 * 64];   // Asm | Bsm = 32 KB; reused for C-stage
    ushort* Asm = smem;
    ushort* Bsm = smem + 128 * 64;

    const int t    = threadIdx.x;
    const int lane = t & 63;
    const int wid  = t >> 6;
    const int wm   = wid >> 1;
    const int wn   = wid & 1;
    const int l16  = lane & 15;
    const int sl0  = lane >> 4;         // 0..3: 16B slot base within K-half
    const int g4   = (lane >> 4) * 4;

    const int srow = lane >> 3;         // staging: row within 8-row stripe
    const int ssl  = (lane & 7) ^ srow; // staging: swizzled k-slot

    const int rb = blockIdx.y * 128;    // M tile
    const int cb = blockIdx.x * 128;    // N tile (over NH1=512)

    f32x4 acc[4][4] = {};

    for (int ks = 0; ks < 12; ++ks) {
        const int k0 = ks * 64;
        __syncthreads();   // prior MFMA reads done before LDS overwrite
        #pragma unroll
        for (int i = 0; i < 4; ++i) {
            const int stripe = wid * 4 + i;         // 0..15
            const int row    = stripe * 8 + srow;
            gload_lds16(&embb[(size_t)(rb + row) * DD + k0 + ssl * 8],
                        &Asm[stripe * 512]);
            gload_lds16(&W1t [(size_t)(cb + row) * DD + k0 + ssl * 8],
                        &Bsm[stripe * 512]);
        }
        __syncthreads();   // vmcnt(0) drain + barrier -> staged visible

        #pragma unroll
        for (int kk = 0; kk < 2; ++kk) {
            const int slot = kk * 4 + sl0;          // 0..7
            bf16x8 af[4], bfr[4];
            #pragma unroll
            for (int m = 0; m < 4; ++m) {
                const int R = wm * 64 + m * 16 + l16;
                af[m] = *(const bf16x8*)&Asm[R * 64 + (slot ^ (R & 7)) * 8];
            }
            #pragma unroll
            for (int n = 0; n < 4; ++n) {
                const int R = wn * 64 + n * 16 + l16;
                bfr[n] = *(const bf16x8*)&Bsm[R * 64 + (slot ^ (R & 7)) * 8];
            }
            #pragma unroll
            for (int m = 0; m < 4; ++m)
                #pragma unroll
                for (int n = 0; n < 4; ++n)
                    acc[m][n] = __builtin_amdgcn_mfma_f32_16x16x32_bf16(
                        af[m], bfr[n], acc[m][n], 0, 0, 0);
        }
    }

    float bv[4];
    #pragma unroll
    for (int n = 0; n < 4; ++n)
        bv[n] = b1[cb + wn * 64 + n * 16 + l16];

    __syncthreads();
    #pragma unroll
    for (int m = 0; m < 4; ++m)
        #pragma unroll
        for (int n = 0; n < 4; ++n)
            #pragma unroll
            for (int j = 0; j < 4; ++j)
                smem[(wm * 64 + m * 16 + g4 + j) * 128 + wn * 64 + n * 16 + l16] =
                    f2bf(acc[m][n][j] + bv[n]);
    __syncthreads();
    #pragma unroll
    for (int i = 0; i < 8; ++i) {
        int ch  = t + i * 256;              // 2048 chunks of 16 B
        int row = ch >> 4;
        int q   = ch & 15;
        *(int4*)&h1raw[(size_t)(rb + row) * NH1 + cb + q * 8] =
            *(const int4*)&smem[row * 128 + q * 8];
    }
}

// ---------------------------------------------------------------------------
// k2 (MFMA, fused LN1+relu on input + LN2+relu on output):
// h2 = relu(LN2(relu(LN1(h1raw)) @ W2 + b2)) stored bf16.
// Round-13: absorbs k1_ln. M-tile 32 rows; prologue stages full 32x512 h1raw
// panel (8 swizzled K-subtiles, 32 KB) via gload_lds, applies LN1+relu in
// LDS, then the K-loop reads A from LDS (staged once). 66 KB -> 2 blocks/CU.
__global__ __launch_bounds__(512) void k2_mfma(
    const ushort* __restrict__ h1raw, const ushort* __restrict__ W2t,
    const float* __restrict__ g1, const float* __restrict__ be1,
    const float* __restrict__ b2, const float* __restrict__ g2,
    const float* __restrict__ be2, ushort* __restrict__ h2)
{
    __shared__ ushort Ah[8 * 2048];     // 32 KB: 8 subtiles [4 stripes][512]
    __shared__ ushort Bsm[256 * 64];    // 32 KB
    __shared__ float red[8][32][2];
    __shared__ float stats[32][2];

    const int t    = threadIdx.x;
    const int lane = t & 63;
    const int wid  = t >> 6;            // 0..7 (wave owns cols wid*32..+32)
    const int l16  = lane & 15;
    const int sl0  = lane >> 4;
    const int g4   = (lane >> 4) * 4;
    const int rb   = blockIdx.x * 32;

    const int srow = lane >> 3;
    const int ssl  = (lane & 7) ^ srow;

    // prologue: stage full A panel (32 rows x 512) -- 32 stripes, 4/wave
    #pragma unroll
    for (int i = 0; i < 4; ++i) {
        const int s  = wid * 4 + i;     // 0..31
        const int ks = s >> 2;          // K-subtile 0..7
        const int st = s & 3;           // stripe within subtile 0..3
        const int row = st * 8 + srow;
        gload_lds16(&h1raw[(size_t)(rb + row) * NH1 + ks * 64 + ssl * 8],
                    &Ah[ks * 2048 + st * 512]);
    }
    __syncthreads();

    // LN1 + relu in LDS: 16 threads/row, 32 elems each (subtile j>>1, half j&1)
    {
        const int r  = t >> 4;          // row 0..31
        const int j  = t & 15;
        const int ks = j >> 1;
        const int hf = j & 1;
        ushort u[4][8];
        float s = 0.f, q2 = 0.f;
        #pragma unroll
        for (int qi = 0; qi < 4; ++qi) {
            const int q = hf * 4 + qi;
            *(int4*)u[qi] = *(const int4*)
                &Ah[ks * 2048 + (r >> 3) * 512 + (r & 7) * 64 + ((q ^ (r & 7)) * 8)];
            #pragma unroll
            for (int e = 0; e < 8; ++e) {
                float x = bf2f(u[qi][e]);
                s += x; q2 += x * x;
            }
        }
        #pragma unroll
        for (int off = 8; off; off >>= 1) {
            s  += __shfl_xor(s, off);
            q2 += __shfl_xor(q2, off);
        }
        const float mu  = s * (1.f / NH1);
        const float var = q2 * (1.f / NH1) - mu * mu;
        const float rs  = rsqrtf(var + 1e-5f);
        #pragma unroll
        for (int qi = 0; qi < 4; ++qi) {
            const int q = hf * 4 + qi;
            const int col = ks * 64 + q * 8;
            float gv[8], ev[8];
            *(float4*)&gv[0] = *(const float4*)&g1[col];
            *(float4*)&gv[4] = *(const float4*)&g1[col + 4];
            *(float4*)&ev[0] = *(const float4*)&be1[col];
            *(float4*)&ev[4] = *(const float4*)&be1[col + 4];
            #pragma unroll
            for (int e = 0; e < 8; ++e) {
                float x = bf2f(u[qi][e]);
                u[qi][e] = f2bf(fmaxf(fmaf((x - mu) * rs, gv[e], ev[e]), 0.f));
            }
            *(int4*)&Ah[ks * 2048 + (r >> 3) * 512 + (r & 7) * 64 + ((q ^ (r & 7)) * 8)]
                = *(int4*)u[qi];
        }
    }
    // (visibility of LN1 writes is ordered by the post-B-stage barrier below)

    f32x4 acc[2][2] = {};

    for (int ks = 0; ks < 8; ++ks) {
        const int k0 = ks * 64;
        __syncthreads();    // Bsm safe to overwrite; orders LN1 writes at ks=0
        #pragma unroll
        for (int i = 0; i < 4; ++i) {
            const int s   = wid * 4 + i;    // 0..31 stripes of B (256 rows)
            const int row = s * 8 + srow;
            gload_lds16(&W2t[(size_t)row * NH1 + k0 + ssl * 8],
                        &Bsm[s * 512]);
        }
        __syncthreads();

        #pragma unroll
        for (int kk = 0; kk < 2; ++kk) {
            const int slot = kk * 4 + sl0;
            bf16x8 af[2], bfr[2];
            #pragma unroll
            for (int m = 0; m < 2; ++m) {
                const int R = m * 16 + l16;         // 0..31
                af[m] = *(const bf16x8*)
                    &Ah[ks * 2048 + R * 64 + (slot ^ (R & 7)) * 8];
            }
            #pragma unroll
            for (int n = 0; n < 2; ++n) {
                const int R = wid * 32 + n * 16 + l16;   // 0..255
                bfr[n] = *(const bf16x8*)&Bsm[R * 64 + (slot ^ (R & 7)) * 8];
            }
            #pragma unroll
            for (int m = 0; m < 2; ++m)
                #pragma unroll
                for (int n = 0; n < 2; ++n)
                    acc[m][n] = __builtin_amdgcn_mfma_f32_16x16x32_bf16(
                        af[m], bfr[n], acc[m][n], 0, 0, 0);
        }
    }

    // bias + LN2
    float bv[2];
    #pragma unroll
    for (int n = 0; n < 2; ++n) bv[n] = b2[wid * 32 + n * 16 + l16];
    #pragma unroll
    for (int m = 0; m < 2; ++m)
        #pragma unroll
        for (int n = 0; n < 2; ++n)
            #pragma unroll
            for (int j = 0; j < 4; ++j) acc[m][n][j] += bv[n];

    #pragma unroll
    for (int m = 0; m < 2; ++m)
        #pragma unroll
        for (int j = 0; j < 4; ++j) {
            float p = 0.f, q = 0.f;
            #pragma unroll
            for (int n = 0; n < 2; ++n) {
                float v = acc[m][n][j];
                p += v; q += v * v;
            }
            #pragma unroll
            for (int off = 8; off; off >>= 1) {
                p += __shfl_xor(p, off);
                q += __shfl_xor(q, off);
            }
            if (l16 == 0) {
                red[wid][m * 16 + g4 + j][0] = p;
                red[wid][m * 16 + g4 + j][1] = q;
            }
        }
    __syncthreads();
    if (t < 32) {
        float S = 0.f, S2 = 0.f;
        #pragma unroll
        for (int w = 0; w < 8; ++w) { S += red[w][t][0]; S2 += red[w][t][1]; }
        float mu  = S  * (1.f / NH2);
        float var = S2 * (1.f / NH2) - mu * mu;
        stats[t][0] = mu;
        stats[t][1] = rsqrtf(var + 1e-5f);
    }
    __syncthreads();

    float gv[2], ev[2];
    #pragma unroll
    for (int n = 0; n < 2; ++n) {
        int col = wid * 32 + n * 16 + l16;
        gv[n] = g2[col]; ev[n] = be2[col];
    }
    ushort* dst = h2 + (size_t)rb * NH2;
    #pragma unroll
    for (int m = 0; m < 2; ++m)
        #pragma unroll
        for (int j = 0; j < 4; ++j) {
            int row = m * 16 + g4 + j;
            float mu = stats[row][0], rs = stats[row][1];
            #pragma unroll
            for (int n = 0; n < 2; ++n) {
                float val = fmaxf(fmaf((acc[m][n][j] - mu) * rs, gv[n], ev[n]), 0.f);
                dst[(size_t)row * NH2 + wid * 32 + n * 16 + l16] = f2bf(val);
            }
        }
}

// ---------------------------------------------------------------------------
// k3a: W_flat(bf16) = h2 @ Wd + bd, packed into second half of out rows.
// global_load_lds + XOR-swizzle staging.
__global__ __launch_bounds__(256) void k_gemm_wd_mfma(
    const ushort* __restrict__ h2, const ushort* __restrict__ Wdt,
    const float* __restrict__ bd, ushort* __restrict__ outw)
{
    __shared__ ushort smem[2 * 128 * 64];   // Asm | Bsm = 32 KB; reused for C-stage
    ushort* Asm = smem;
    ushort* Bsm = smem + 128 * 64;

    const int t    = threadIdx.x;
    const int lane = t & 63;
    const int wid  = t >> 6;
    const int wm   = wid >> 1;
    const int wn   = wid & 1;
    const int l16  = lane & 15;
    const int sl0  = lane >> 4;
    const int g4   = (lane >> 4) * 4;

    const int srow = lane >> 3;
    const int ssl  = (lane & 7) ^ srow;

    const int rb = blockIdx.y * 128;
    const int cb = blockIdx.x * 128;

    f32x4 acc[4][4] = {};

    for (int ks = 0; ks < 4; ++ks) {
        const int k0 = ks * 64;
        __syncthreads();
        #pragma unroll
        for (int i = 0; i < 4; ++i) {
            const int stripe = wid * 4 + i;
            const int row    = stripe * 8 + srow;
            gload_lds16(&h2 [(size_t)(rb + row) * NH2 + k0 + ssl * 8],
                        &Asm[stripe * 512]);
            gload_lds16(&Wdt[(size_t)(cb + row) * NH2 + k0 + ssl * 8],
                        &Bsm[stripe * 512]);
        }
        __syncthreads();

        #pragma unroll
        for (int kk = 0; kk < 2; ++kk) {
            const int slot = kk * 4 + sl0;
            bf16x8 af[4], bfr[4];
            #pragma unroll
            for (int m = 0; m < 4; ++m) {
                const int R = wm * 64 + m * 16 + l16;
                af[m] = *(const bf16x8*)&Asm[R * 64 + (slot ^ (R & 7)) * 8];
            }
            #pragma unroll
            for (int n = 0; n < 4; ++n) {
                const int R = wn * 64 + n * 16 + l16;
                bfr[n] = *(const bf16x8*)&Bsm[R * 64 + (slot ^ (R & 7)) * 8];
            }
            #pragma unroll
            for (int m = 0; m < 4; ++m)
                #pragma unroll
                for (int n = 0; n < 4; ++n)
                    acc[m][n] = __builtin_amdgcn_mfma_f32_16x16x32_bf16(
                        af[m], bfr[n], acc[m][n], 0, 0, 0);
        }
    }

    float bv[4];
    #pragma unroll
    for (int n = 0; n < 4; ++n)
        bv[n] = bd[cb + wn * 64 + n * 16 + l16];

    __syncthreads();
    #pragma unroll
    for (int m = 0; m < 4; ++m)
        #pragma unroll
        for (int n = 0; n < 4; ++n)
            #pragma unroll
            for (int j = 0; j < 4; ++j)
                smem[(wm * 64 + m * 16 + g4 + j) * 128 + wn * 64 + n * 16 + l16] =
                    f2bf(acc[m][n][j] + bv[n]);
    __syncthreads();
    #pragma unroll
    for (int i = 0; i < 8; ++i) {
        int ch  = t + i * 256;
        int row = ch >> 4;
        int q   = ch & 15;
        *(int4*)&outw[(size_t)(rb + row) * 6144 + 3072 + cb + q * 8] =
            *(const int4*)&smem[row * 128 + q * 8];
    }
}

// ---------------------------------------------------------------------------
// k3b (MFMA, fused softmax + Gram-Schmidt): attn = softmax(h2 @ Wa + ba);
// then per row W = Wflat_bf16 * attn, modified GS, normalize -> out.
__global__ __launch_bounds__(512) void k_attn_gs_mfma(
    const ushort* __restrict__ h2, const ushort* __restrict__ Wat,
    const float* __restrict__ ba, float* __restrict__ out)
{
    __shared__ ushort Asm[64 * 64];      //  8 KB
    __shared__ ushort Bsm[768 * 64];     // 96 KB (reused as f32 stage [32][768])
    __shared__ float red[8][64];
    __shared__ float stats[64];

    const int t    = threadIdx.x;
    const int lane = t & 63;
    const int wid  = t >> 6;            // 0..7
    const int wm   = wid >> 2;          // 0..1
    const int wn   = wid & 3;           // 0..3
    const int l16  = lane & 15;
    const int sl0  = lane >> 4;
    const int g4   = (lane >> 4) * 4;
    const int rb   = blockIdx.x * 64;

    const int srow = lane >> 3;
    const int ssl  = (lane & 7) ^ srow;

    float* attn = out + (size_t)BSZ * (KK * DD);

    f32x4 acc[2][12] = {};

    for (int ks = 0; ks < 4; ++ks) {
        const int k0 = ks * 64;
        __syncthreads();
        {
            const int row = wid * 8 + srow;
            gload_lds16(&h2[(size_t)(rb + row) * NH2 + k0 + ssl * 8],
                        &Asm[wid * 512]);
        }
        #pragma unroll
        for (int i = 0; i < 12; ++i) {
            const int stripe = wid * 12 + i;
            const int row    = stripe * 8 + srow;
            gload_lds16(&Wat[(size_t)row * NH2 + k0 + ssl * 8],
                        &Bsm[stripe * 512]);
        }
        __syncthreads();

        #pragma unroll
        for (int kk = 0; kk < 2; ++kk) {
            const int slot = kk * 4 + sl0;
            bf16x8 af[2], bfr[12];
            #pragma unroll
            for (int m = 0; m < 2; ++m) {
                const int R = wm * 32 + m * 16 + l16;
                af[m] = *(const bf16x8*)&Asm[R * 64 + (slot ^ (R & 7)) * 8];
            }
            #pragma unroll
            for (int n = 0; n < 12; ++n) {
                const int R = wn * 192 + n * 16 + l16;
                bfr[n] = *(const bf16x8*)&Bsm[R * 64 + (slot ^ (R & 7)) * 8];
            }
            #pragma unroll
            for (int m = 0; m < 2; ++m)
                #pragma unroll
                for (int n = 0; n < 12; ++n)
                    acc[m][n] = __builtin_amdgcn_mfma_f32_16x16x32_bf16(
                        af[m], bfr[n], acc[m][n], 0, 0, 0);
        }
    }

    // bias
    float bb[12];
    #pragma unroll
    for (int n = 0; n < 12; ++n) bb[n] = ba[wn * 192 + n * 16 + l16];
    #pragma unroll
    for (int m = 0; m < 2; ++m)
        #pragma unroll
        for (int n = 0; n < 12; ++n)
            #pragma unroll
            for (int j = 0; j < 4; ++j) acc[m][n][j] += bb[n];

    // row max
    #pragma unroll
    for (int m = 0; m < 2; ++m)
        #pragma unroll
        for (int j = 0; j < 4; ++j) {
            float p = acc[m][0][j];
            #pragma unroll
            for (int n = 1; n < 12; ++n) p = fmaxf(p, acc[m][n][j]);
            #pragma unroll
            for (int off = 8; off; off >>= 1) p = fmaxf(p, __shfl_xor(p, off));
            if (l16 == 0) red[wid][wm * 32 + m * 16 + g4 + j] = p;
        }
    __syncthreads();
    if (t < 64) {
        const int w0 = (t >> 5) * 4;
        stats[t] = fmaxf(fmaxf(red[w0][t], red[w0 + 1][t]),
                         fmaxf(red[w0 + 2][t], red[w0 + 3][t]));
    }
    __syncthreads();
    // exp + row sum
    #pragma unroll
    for (int m = 0; m < 2; ++m)
        #pragma unroll
        for (int j = 0; j < 4; ++j) {
            float M = stats[wm * 32 + m * 16 + g4 + j];
            float s = 0.f;
            #pragma unroll
            for (int n = 0; n < 12; ++n) {
                acc[m][n][j] = __expf(acc[m][n][j] - M);
                s += acc[m][n][j];
            }
            #pragma unroll
            for (int off = 8; off; off >>= 1) s += __shfl_xor(s, off);
            if (l16 == 0) red[wid][wm * 32 + m * 16 + g4 + j] = s;
        }
    __syncthreads();
    if (t < 64) {
        const int w0 = (t >> 5) * 4;
        stats[t] = 1.f / (red[w0][t] + red[w0 + 1][t] + red[w0 + 2][t] + red[w0 + 3][t]);
    }
    __syncthreads();

    // two 32-row passes: stage scaled attn -> write attn -> GS those rows
    float* stage = (float*)Bsm;
    #pragma unroll
    for (int h = 0; h < 2; ++h) {
        if (wm == h) {
            #pragma unroll
            for (int m = 0; m < 2; ++m)
                #pragma unroll
                for (int j = 0; j < 4; ++j) {
                    const int r = m * 16 + g4 + j;
                    const float inv = stats[h * 32 + r];
                    #pragma unroll
                    for (int n = 0; n < 12; ++n)
                        stage[r * 768 + wn * 192 + n * 16 + l16] = acc[m][n][j] * inv;
                }
        }
        __syncthreads();
        // coalesced attn output
        #pragma unroll
        for (int i = 0; i < 12; ++i) {
            int ch  = t + i * 512;          // 6144 chunks of 16 B
            int row = ch / 192;
            int q   = ch - row * 192;
            *(float4*)&attn[(size_t)(rb + h * 32 + row) * DD + q * 4] =
                *(const float4*)&stage[row * 768 + q * 4];
        }
        // Gram-Schmidt: wave wid owns rows wid*4 .. wid*4+3 of this half
        for (int rr = 0; rr < 4; ++rr) {
            const int rl = wid * 4 + rr;
            const size_t row = (size_t)rb + h * 32 + rl;
            float a[12];
            #pragma unroll
            for (int k = 0; k < 3; ++k)
                *(float4*)&a[k * 4] =
                    *(const float4*)&stage[rl * 768 + lane * 4 + 256 * k];

            const ushort* wsrc = (const ushort*)out + row * 6144 + 3072;
            float* Wf = out + row * (KK * DD);
            float w[4][12];
            #pragma unroll
            for (int i = 0; i < 4; ++i) {
                #pragma unroll
                for (int k = 0; k < 3; ++k) {
                    ushort4 uv = *(const ushort4*)&wsrc[i * DD + lane * 4 + 256 * k];
                    w[i][k * 4 + 0] = bf2f(uv.x) * a[k * 4 + 0];
                    w[i][k * 4 + 1] = bf2f(uv.y) * a[k * 4 + 1];
                    w[i][k * 4 + 2] = bf2f(uv.z) * a[k * 4 + 2];
                    w[i][k * 4 + 3] = bf2f(uv.w) * a[k * 4 + 3];
                }
            }
            #pragma unroll
            for (int i = 0; i < 4; ++i) {
                #pragma unroll
                for (int p = 0; p < i; ++p) {
                    float s2 = 0.f;
                    #pragma unroll
                    for (int j = 0; j < 12; ++j) s2 = fmaf(w[i][j], w[p][j], s2);
                    #pragma unroll
                    for (int off = 32; off; off >>= 1) s2 += __shfl_xor(s2, off);
                    #pragma unroll
                    for (int j = 0; j < 12; ++j) w[i][j] = fmaf(-s2, w[p][j], w[i][j]);
                }
                float n2 = 0.f;
                #pragma unroll
                for (int j = 0; j < 12; ++j) n2 = fmaf(w[i][j], w[i][j], n2);
                #pragma unroll
                for (int off = 32; off; off >>= 1) n2 += __shfl_xor(n2, off);
                float invn = 1.f / fmaxf(sqrtf(n2), 1e-12f);
                #pragma unroll
                for (int j = 0; j < 12; ++j) w[i][j] *= invn;
            }
            #pragma unroll
            for (int i = 0; i < 4; ++i) {
                #pragma unroll
                for (int k = 0; k < 3; ++k) {
                    float4 wv;
                    wv.x = w[i][k * 4 + 0]; wv.y = w[i][k * 4 + 1];
                    wv.z = w[i][k * 4 + 2]; wv.w = w[i][k * 4 + 3];
                    *(float4*)&Wf[i * DD + lane * 4 + 256 * k] = wv;
                }
            }
        }
        __syncthreads();    // stage reads done before next half overwrites
    }
}

// ---------------------------------------------------------------------------
extern "C" void kernel_launch(void* const* d_in, const int* in_sizes, int n_in,
                              void* d_out, int out_size, void* d_ws, size_t ws_size,
                              hipStream_t stream)
{
    const float* emb = (const float*)d_in[0];
    const float* W1  = (const float*)d_in[1];
    const float* b1  = (const float*)d_in[2];
    const float* g1  = (const float*)d_in[3];
    const float* be1 = (const float*)d_in[4];
    const float* W2  = (const float*)d_in[5];
    const float* b2  = (const float*)d_in[6];
    const float* g2  = (const float*)d_in[7];
    const float* be2 = (const float*)d_in[8];
    const float* Wd  = (const float*)d_in[9];
    const float* bd  = (const float*)d_in[10];
    const float* Wa  = (const float*)d_in[11];
    const float* ba  = (const float*)d_in[12];

    float* out = (float*)d_out;
    ushort* h1   = (ushort*)d_ws;                // B*512 bf16 = 16.8 MB (pre-LN)
    ushort* h2   = h1 + (size_t)BSZ * NH1;       // B*256 bf16 =  8.4 MB
    ushort* Wdt  = h2 + (size_t)BSZ * NH2;       // 3072*256 bf16 = 1.5 MB
    ushort* W1t  = Wdt + (size_t)ND * NH2;       // 512*768 bf16 = 0.77 MB
    ushort* W2t  = W1t + (size_t)NH1 * DD;       // 256*512 bf16 = 0.25 MB
    ushort* Wat  = W2t + (size_t)NH2 * NH1;      // 768*256 bf16 = 0.39 MB
    ushort* embb = Wat + (size_t)DD * NH2;       // B*768 bf16 = 25.2 MB

    hipLaunchKernelGGL(k_prep, dim3(3520), dim3(256), 0, stream,
                       emb, embb, W1, W1t, W2, W2t, Wd, Wdt, Wa, Wat);
    hipLaunchKernelGGL(k1_gemm, dim3(NH1 / 128, BSZ / 128), dim3(256), 0, stream,
                       embb, W1t, b1, h1);
    hipLaunchKernelGGL(k2_mfma, dim3(BSZ / 32), dim3(512), 0, stream,
                       h1, W2t, g1, be1, b2, g2, be2, h2);
    hipLaunchKernelGGL(k_gemm_wd_mfma, dim3(ND / 128, BSZ / 128), dim3(256), 0, stream,
                       h2, Wdt, bd, (ushort*)out);
    hipLaunchKernelGGL(k_attn_gs_mfma, dim3(BSZ / 64), dim3(512), 0, stream,
                       h2, Wat, ba, out);
}